// Round 1
// baseline (8279.863 us; speedup 1.0000x reference)
//
#include <hip/hip_runtime.h>
#include <math.h>

// ---------------- problem constants ----------------
#define NN 50000      // nodes
#define MM 12         // neighbors
#define NM 600000     // edges = NN*MM
#define OF 92         // orig node features
#define FF 64         // node feature dim
#define EE 41         // edge feature dim
#define ZZ 169        // 2*FF + EE
#define WSP 256       // packed weight stride (cols): nf@0, nc@64, ef@128, ec@192
#define EFO 128
#define ECO 192
#define ROWS 60       // rows (edges) per block = 5 nodes * 12
#define NPB 5         // nodes per block
#define NBLK 10000    // NN / NPB

__device__ __forceinline__ float lrelu(float x){ return x > 0.f ? x : 0.01f*x; }
__device__ __forceinline__ float sigm(float x){ return 1.f/(1.f+expf(-x)); }
__device__ __forceinline__ float softpl(float x){ return fmaxf(x,0.f) + log1pf(expf(-fabsf(x))); }

// ---------------- weight packing ----------------
// conv layer l: [169][256]: c<128 -> W_pre_node[l][k][c]; 128..168 -> ef = W_pre_edge[l][k][c-128];
// 192..232 -> ec = W_pre_edge[l][k][41 + c-192]; else 0
__global__ __launch_bounds__(256) void pack_conv(const float* __restrict__ Wn,
    const float* __restrict__ We, float* __restrict__ dst)
{
    int idx = blockIdx.x*256 + threadIdx.x;
    if (idx >= 3*ZZ*WSP) return;
    int l = idx / (ZZ*WSP);
    int rem = idx - l*ZZ*WSP;
    int k = rem / WSP;
    int c = rem - k*WSP;
    float v = 0.f;
    if (c < 128)                 v = Wn[(l*ZZ + k)*128 + c];
    else if (c >= EFO && c < EFO+EE) v = We[(l*ZZ + k)*82 + (c - EFO)];
    else if (c >= ECO && c < ECO+EE) v = We[(l*ZZ + k)*82 + 41 + (c - ECO)];
    dst[idx] = v;
}

// final: [169][256]: c<128 -> W_dist[k][c]; else W_const[k][c-128]
__global__ __launch_bounds__(256) void pack_fin(const float* __restrict__ Wd,
    const float* __restrict__ Wc, float* __restrict__ dst)
{
    int idx = blockIdx.x*256 + threadIdx.x;
    if (idx >= ZZ*WSP) return;
    int k = idx / WSP;
    int c = idx - k*WSP;
    dst[idx] = (c < 128) ? Wd[k*128 + c] : Wc[k*128 + (c-128)];
}

// ---------------- distance ----------------
__global__ __launch_bounds__(256) void k_dist(const float* __restrict__ off,
    const float* __restrict__ apos, const float* __restrict__ cells,
    const int* __restrict__ eidx, float* __restrict__ distb)
{
    int idx = blockIdx.x*256 + threadIdx.x;
    if (idx >= NM) return;
    int n = idx / MM;
    const float* o  = off + (size_t)idx*3;
    const float* cl = cells + (size_t)n*9;
    int n2 = eidx[idx];
    float o0=o[0], o1=o[1], o2=o[2];
    float dd = 1e-12f;
    #pragma unroll
    for (int j=0;j<3;j++){
        float oc = o0*cl[0*3+j] + o1*cl[1*3+j] + o2*cl[2*3+j];
        float d = apos[(size_t)n2*3+j] + oc - apos[(size_t)n*3+j];
        dd += d*d;
    }
    distb[idx] = sqrtf(dd);
}

// ---------------- embedding: node0 = node_fea @ W_emb + b_emb ----------------
__global__ __launch_bounds__(256) void k_emb(const float* __restrict__ nf,
    const float* __restrict__ W, const float* __restrict__ b, float* __restrict__ node0)
{
    int idx = blockIdx.x*256 + threadIdx.x;
    if (idx >= NN*FF) return;
    int n = idx >> 6, c = idx & 63;
    float s = b[c];
    for (int k=0;k<OF;k++) s = fmaf(nf[(size_t)n*OF+k], W[k*FF+c], s);
    node0[idx] = s;
}

// ---------------- z staging into LDS (k-major [176][64]) ----------------
__device__ __forceinline__ void stage_z(float* __restrict__ Zl,
    const float* __restrict__ node_src, const float* __restrict__ edge_src,
    const int* __restrict__ eidx, int n0, int tid)
{
    const int gr0 = n0 * MM;
    for (int i = tid; i < 44*64; i += 256) {
        int r  = i & 63;
        int kq = i >> 6;          // 0..43 (float4 index along k)
        float4 v = make_float4(0.f,0.f,0.f,0.f);
        if (r < ROWS) {
            int gr = gr0 + r;
            if (kq < 16) {                       // self node, k = 4*kq
                int n = n0 + r / MM;
                v = *(const float4*)&node_src[(size_t)n*FF + kq*4];
            } else if (kq < 32) {                // neighbor node
                int n2 = eidx[gr];
                v = *(const float4*)&node_src[(size_t)n2*FF + (kq-16)*4];
            } else if (kq < 43) {                // edge features (41 wide)
                int c0 = (kq - 32) * 4;
                const float* es = edge_src + (size_t)gr*EE;
                v.x = es[c0];
                if (c0+1 < EE) v.y = es[c0+1];
                if (c0+2 < EE) v.z = es[c0+2];
                if (c0+3 < EE) v.w = es[c0+3];
            }
        }
        int k = kq*4;
        Zl[(k+0)*64 + r] = v.x;
        Zl[(k+1)*64 + r] = v.y;
        Zl[(k+2)*64 + r] = v.z;
        Zl[(k+3)*64 + r] = v.w;
    }
}

// ---------------- GEMM inner loop: 4 rows x 16 cols per thread ----------------
// accA: cols {4tx..4tx+3, 64+4tx..}  accB: cols {128+4tx.., 192+4tx..}
__device__ __forceinline__ void gemm_core(const float* __restrict__ Zl,
    const float* __restrict__ Wc, int tr, int tx,
    float (&accA)[4][8], float (&accB)[4][8])
{
    #pragma unroll
    for (int i=0;i<4;i++)
        #pragma unroll
        for (int j=0;j<8;j++){ accA[i][j]=0.f; accB[i][j]=0.f; }

    for (int k=0;k<ZZ;k++){
        float4 a4 = *(const float4*)&Zl[k*64 + 4*tr];
        const float* wr = Wc + (size_t)k*WSP;
        float4 w0 = *(const float4*)(wr + 4*tx);
        float4 w1 = *(const float4*)(wr + 64 + 4*tx);
        float4 w2 = *(const float4*)(wr + EFO + 4*tx);
        float4 w3 = *(const float4*)(wr + ECO + 4*tx);
        float av[4] = {a4.x,a4.y,a4.z,a4.w};
        float wn[8] = {w0.x,w0.y,w0.z,w0.w, w1.x,w1.y,w1.z,w1.w};
        float we[8] = {w2.x,w2.y,w2.z,w2.w, w3.x,w3.y,w3.z,w3.w};
        #pragma unroll
        for (int i=0;i<4;i++){
            #pragma unroll
            for (int j=0;j<8;j++){
                accA[i][j] = fmaf(av[i], wn[j], accA[i][j]);
                accB[i][j] = fmaf(av[i], we[j], accB[i][j]);
            }
        }
    }
}

// ---------------- block column reduction + global atomic accumulate ----------------
__device__ __forceinline__ void red_accum(float* __restrict__ red, int tid,
    const float p[4], float* __restrict__ gout, int ncols)
{
    int tr = tid >> 4, tx = tid & 15;
    __syncthreads();   // protect WAR vs previous round's readers
    red[tr*64 + 4*tx+0] = p[0];
    red[tr*64 + 4*tx+1] = p[1];
    red[tr*64 + 4*tx+2] = p[2];
    red[tr*64 + 4*tx+3] = p[3];
    __syncthreads();
    if (tid < ncols) {
        float s = 0.f;
        #pragma unroll
        for (int t=0;t<16;t++) s += red[t*64 + tid];
        atomicAdd(&gout[tid], s);
    }
}

// ---------------- stats pass: per-channel sum & sumsq of z@W ----------------
__global__ __launch_bounds__(256,3) void k_stats(
    const float* __restrict__ node_src, const float* __restrict__ edge_src,
    const int* __restrict__ eidx, const float* __restrict__ Wc,
    float* __restrict__ sumv, float* __restrict__ sumq, int g2w, int g3w)
{
    __shared__ float Zl[176*64];
    __shared__ float red[16*64];
    const int tid = threadIdx.x, tr = tid>>4, tx = tid&15;
    const int n0 = blockIdx.x * NPB;
    stage_z(Zl, node_src, edge_src, eidx, n0, tid);
    __syncthreads();
    float accA[4][8], accB[4][8];
    gemm_core(Zl, Wc, tr, tx, accA, accB);

    float pv[4], qv[4];
    // group 0 (cols 0..63)
    #pragma unroll
    for (int j=0;j<4;j++){ float s=0,ss=0;
        #pragma unroll
        for (int i=0;i<4;i++){ float v=accA[i][j]; s+=v; ss+=v*v; }
        pv[j]=s; qv[j]=ss; }
    red_accum(red,tid,pv,sumv+0,64);
    red_accum(red,tid,qv,sumq+0,64);
    // group 1 (cols 64..127)
    #pragma unroll
    for (int j=0;j<4;j++){ float s=0,ss=0;
        #pragma unroll
        for (int i=0;i<4;i++){ float v=accA[i][4+j]; s+=v; ss+=v*v; }
        pv[j]=s; qv[j]=ss; }
    red_accum(red,tid,pv,sumv+64,64);
    red_accum(red,tid,qv,sumq+64,64);
    // group 2 (cols 128..)
    #pragma unroll
    for (int j=0;j<4;j++){ float s=0,ss=0;
        #pragma unroll
        for (int i=0;i<4;i++){ float v=accB[i][j]; s+=v; ss+=v*v; }
        bool ok = (4*tx+j) < g2w; pv[j]= ok? s:0.f; qv[j]= ok? ss:0.f; }
    red_accum(red,tid,pv,sumv+EFO,g2w);
    red_accum(red,tid,qv,sumq+EFO,g2w);
    // group 3 (cols 192..)
    #pragma unroll
    for (int j=0;j<4;j++){ float s=0,ss=0;
        #pragma unroll
        for (int i=0;i<4;i++){ float v=accB[i][4+j]; s+=v; ss+=v*v; }
        bool ok = (4*tx+j) < g3w; pv[j]= ok? s:0.f; qv[j]= ok? ss:0.f; }
    red_accum(red,tid,pv,sumv+ECO,g3w);
    red_accum(red,tid,qv,sumq+ECO,g3w);
}

// ---------------- finalize: mean / invstd ----------------
__global__ __launch_bounds__(256) void k_fin(const float* __restrict__ s,
    const float* __restrict__ q, float* __restrict__ m, float* __restrict__ istd,
    float inv_cnt, int ncols)
{
    int t = threadIdx.x;
    if (t < ncols) {
        float mm = s[t]*inv_cnt;
        float v  = q[t]*inv_cnt - mm*mm;
        m[t] = mm;
        istd[t] = rsqrtf(v + 1e-5f);
    }
}

// ---------------- apply pass (conv): BN + gates, aggr + g, aggr/g stats ----------------
__global__ __launch_bounds__(256,3) void k_apply(
    const float* __restrict__ node_src, const float* __restrict__ edge_src,
    const int* __restrict__ eidx, const float* __restrict__ Wc,
    const float* __restrict__ mPre, const float* __restrict__ iPre,
    float* __restrict__ aggr, float* __restrict__ gbuf,
    float* __restrict__ aS, float* __restrict__ aQ,
    float* __restrict__ gS, float* __restrict__ gQ)
{
    __shared__ float Zl[176*64];
    __shared__ float red[16*64];
    const int tid = threadIdx.x, tr = tid>>4, tx = tid&15;
    const int n0 = blockIdx.x * NPB;
    const int gr0 = n0 * MM;
    stage_z(Zl, node_src, edge_src, eidx, n0, tid);
    __syncthreads();
    float accA[4][8], accB[4][8];
    gemm_core(Zl, Wc, tr, tx, accA, accB);

    // ---- node branch: gate + sum over this thread's 4 rows (same node) ----
    float p[4] = {0.f,0.f,0.f,0.f};
    #pragma unroll
    for (int i=0;i<4;i++){
        #pragma unroll
        for (int j=0;j<4;j++){
            int c = 4*tx+j;
            float nf = (accA[i][j]   - mPre[c])    * iPre[c];
            float nc = (accA[i][4+j] - mPre[64+c]) * iPre[64+c];
            p[j] += sigm(nf)*lrelu(nc);
        }
    }
    red[tr*64+4*tx+0]=p[0]; red[tr*64+4*tx+1]=p[1];
    red[tr*64+4*tx+2]=p[2]; red[tr*64+4*tx+3]=p[3];
    __syncthreads();
    if (tid < 64) {
        float sA=0.f, sQ2=0.f;
        #pragma unroll
        for (int nl=0;nl<NPB;nl++){
            float v = red[(3*nl+0)*64+tid] + red[(3*nl+1)*64+tid] + red[(3*nl+2)*64+tid];
            aggr[(size_t)(n0+nl)*64 + tid] = v;
            sA += v; sQ2 += v*v;
        }
        atomicAdd(&aS[tid], sA);
        atomicAdd(&aQ[tid], sQ2);
    }

    // ---- edge branch: gate, write g, accumulate g stats ----
    float pg[4]={0.f,0.f,0.f,0.f}, pq[4]={0.f,0.f,0.f,0.f};
    #pragma unroll
    for (int i=0;i<4;i++){
        int rl = 4*tr+i;
        bool rv = rl < ROWS;
        #pragma unroll
        for (int j=0;j<4;j++){
            int ce = 4*tx+j;
            if (ce < EE && rv) {
                float ef = (accB[i][j]   - mPre[EFO+ce]) * iPre[EFO+ce];
                float ec = (accB[i][4+j] - mPre[ECO+ce]) * iPre[ECO+ce];
                float gv = sigm(ef)*lrelu(ec);
                gbuf[(size_t)(gr0+rl)*EE + ce] = gv;
                pg[j] += gv; pq[j] += gv*gv;
            }
        }
    }
    red_accum(red, tid, pg, gS, EE);
    red_accum(red, tid, pq, gQ, EE);
}

// ---------------- residual updates ----------------
__global__ __launch_bounds__(256) void k_upd_node(const float* __restrict__ cur,
    const float* __restrict__ aggr, const float* __restrict__ mA,
    const float* __restrict__ iA, float* __restrict__ nxt)
{
    int idx = blockIdx.x*256 + threadIdx.x;
    if (idx >= NN*FF) return;
    int c = idx & 63;
    float v = (aggr[idx] - mA[c]) * iA[c];
    nxt[idx] = lrelu(cur[idx] + v);
}

__global__ __launch_bounds__(256) void k_upd_edge(const float* __restrict__ esrc,
    const float* __restrict__ g, const float* __restrict__ mG,
    const float* __restrict__ iG, float* __restrict__ edst)
{
    int idx = blockIdx.x*256 + threadIdx.x;
    if (idx >= NM*EE) return;
    int c = idx % EE;
    float v = (g[idx] - mG[c]) * iG[c];
    edst[idx] = lrelu(esrc[idx] + v);
}

// ---------------- final heads: BN + softplus + channel means -> out ----------------
__global__ __launch_bounds__(256,3) void k_final(
    const float* __restrict__ node_src, const float* __restrict__ edge_src,
    const int* __restrict__ eidx, const float* __restrict__ Wc,
    const float* __restrict__ mF, const float* __restrict__ iF,
    const float* __restrict__ distb, float* __restrict__ out)
{
    __shared__ float Zl[176*64];
    __shared__ float bufD[64*16];
    __shared__ float bufC[64*16];
    const int tid = threadIdx.x, tr = tid>>4, tx = tid&15;
    const int n0 = blockIdx.x * NPB;
    const int gr0 = n0 * MM;
    stage_z(Zl, node_src, edge_src, eidx, n0, tid);
    __syncthreads();
    float accA[4][8], accB[4][8];
    gemm_core(Zl, Wc, tr, tx, accA, accB);

    #pragma unroll
    for (int i=0;i<4;i++){
        int rl = 4*tr+i;
        float dv = (rl < ROWS) ? distb[gr0 + rl] : 0.f;
        float pd = 0.f, pc = 0.f;
        #pragma unroll
        for (int j=0;j<4;j++){
            int c = 4*tx+j;
            float d0 = (accA[i][j]   - mF[c])      * iF[c]      + dv;
            float d1 = (accA[i][4+j] - mF[64+c])   * iF[64+c]   + dv;
            pd += softpl(d0) + softpl(d1);
            float c0 = (accB[i][j]   - mF[EFO+c])  * iF[EFO+c];
            float c1 = (accB[i][4+j] - mF[ECO+c])  * iF[ECO+c];
            pc += softpl(c0) + softpl(c1);
        }
        bufD[rl*16+tx] = pd;
        bufC[rl*16+tx] = pc;
    }
    __syncthreads();
    if (tid < ROWS) {
        int rl = tid;
        float sd=0.f, sc=0.f;
        #pragma unroll
        for (int t=0;t<16;t++){ sd += bufD[rl*16+t]; sc += bufC[rl*16+t]; }
        size_t gr = gr0 + rl;
        out[gr*2+0] = sd * (1.f/128.f);
        out[gr*2+1] = sc * (1.f/128.f) * (1.f/(float)NN);
    }
}

// ---------------- launch ----------------
extern "C" void kernel_launch(void* const* d_in, const int* in_sizes, int n_in,
                              void* d_out, int out_size, void* d_ws, size_t ws_size,
                              hipStream_t stream)
{
    const float* node_fea = (const float*)d_in[0];
    const float* edge_in  = (const float*)d_in[1];
    const float* nbr_off  = (const float*)d_in[2];
    const float* apos     = (const float*)d_in[3];
    const float* cells    = (const float*)d_in[4];
    const int*   eidx     = (const int*)  d_in[5];
    const float* W_emb    = (const float*)d_in[6];
    const float* b_emb    = (const float*)d_in[7];
    const float* W_pn     = (const float*)d_in[8];
    const float* W_pe     = (const float*)d_in[10];
    const float* W_dist   = (const float*)d_in[12];
    const float* W_cst    = (const float*)d_in[14];
    float* out = (float*)d_out;
    float* wsf = (float*)d_ws;

    size_t o = 0;
    float* node0 = wsf + o; o += (size_t)NN*FF;
    float* node1 = wsf + o; o += (size_t)NN*FF;
    float* edgew = wsf + o; o += (size_t)NM*EE;
    float* gbuf  = wsf + o; o += (size_t)NM*EE;
    float* aggr  = wsf + o; o += (size_t)NN*FF;
    float* distb = wsf + o; o += (size_t)NM;
    float* wcomb = wsf + o; o += (size_t)3*ZZ*WSP;
    float* wfin  = wsf + o; o += (size_t)ZZ*WSP;
    float* stats = wsf + o; o += 4096;
    float* msb   = wsf + o; o += 4096;

    hipMemsetAsync(stats, 0, 4096*sizeof(float), stream);
    pack_conv<<<(3*ZZ*WSP+255)/256, 256, 0, stream>>>(W_pn, W_pe, wcomb);
    pack_fin <<<(ZZ*WSP+255)/256,   256, 0, stream>>>(W_dist, W_cst, wfin);
    k_dist   <<<(NM+255)/256,       256, 0, stream>>>(nbr_off, apos, cells, eidx, distb);
    k_emb    <<<(NN*FF+255)/256,    256, 0, stream>>>(node_fea, W_emb, b_emb, node0);

    const float invNM = 1.f/(float)NM, invN = 1.f/(float)NN;
    const float* ncur = node0;
    const float* ecur = edge_in;

    for (int l=0;l<3;l++){
        float* st = stats + l*736;
        float* ms = msb   + l*736;
        float* preS = st;       float* preQ = st+256;
        float* aS   = st+512;   float* aQ   = st+576;
        float* gS   = st+640;   float* gQ   = st+688;
        float* mPre = ms;       float* iPre = ms+256;
        float* mA   = ms+512;   float* iA   = ms+576;
        float* mG   = ms+640;   float* iG   = ms+688;
        const float* Wl = wcomb + (size_t)l*ZZ*WSP;
        float* ndst = (l & 1) ? node0 : node1;

        k_stats<<<NBLK,256,0,stream>>>(ncur, ecur, eidx, Wl, preS, preQ, EE, EE);
        k_fin  <<<1,256,0,stream>>>(preS, preQ, mPre, iPre, invNM, 256);
        k_apply<<<NBLK,256,0,stream>>>(ncur, ecur, eidx, Wl, mPre, iPre,
                                       aggr, gbuf, aS, aQ, gS, gQ);
        k_fin  <<<1,256,0,stream>>>(aS, aQ, mA, iA, invN, 64);
        k_fin  <<<1,256,0,stream>>>(gS, gQ, mG, iG, invNM, EE);
        k_upd_node<<<(NN*FF+255)/256,256,0,stream>>>(ncur, aggr, mA, iA, ndst);
        k_upd_edge<<<(NM*EE+255)/256,256,0,stream>>>(ecur, gbuf, mG, iG, edgew);
        ncur = ndst;
        ecur = edgew;
    }

    float* fS = stats + 3*736; float* fQ = fS + 256;
    float* mF = msb   + 3*736; float* iF = mF + 256;
    k_stats<<<NBLK,256,0,stream>>>(ncur, ecur, eidx, wfin, fS, fQ, 64, 64);
    k_fin  <<<1,256,0,stream>>>(fS, fQ, mF, iF, invNM, 256);
    k_final<<<NBLK,256,0,stream>>>(ncur, ecur, eidx, wfin, mF, iF, distb, out);
}

// Round 2
// 3384.868 us; speedup vs baseline: 2.4461x; 2.4461x over previous
//
#include <hip/hip_runtime.h>
#include <math.h>

// ---------------- problem constants ----------------
#define NN 50000      // nodes
#define MM 12         // neighbors
#define NM 600000     // edges = NN*MM
#define OF 92         // orig node features
#define FF 64         // node feature dim
#define EE 41         // edge feature dim
#define ZZ 169        // 2*FF + EE
#define EFO 128
#define ECO 192
#define RPB 48        // rows (edges) per block = 4 nodes * 12
#define NPB 4         // nodes per block
#define NBLK 12500    // NN / NPB
#define KP 200        // padded K stride (bf16 elements) in LDS: 400 B = 100 words -> conflict-free b128
#define KSTEPS 6      // 6 * 32 = 192 >= 169

typedef __bf16 bf16x8 __attribute__((ext_vector_type(8)));
typedef float  f32x4  __attribute__((ext_vector_type(4)));

__device__ __forceinline__ float lrelu(float x){ return x > 0.f ? x : 0.01f*x; }
__device__ __forceinline__ float sigm(float x){ return 1.f/(1.f+expf(-x)); }
__device__ __forceinline__ float softpl(float x){ return fmaxf(x,0.f) + log1pf(expf(-fabsf(x))); }
__device__ __forceinline__ unsigned short f2bf(float f){
    __bf16 h = (__bf16)f;
    return __builtin_bit_cast(unsigned short, h);
}

// ---------------- weight packing into B-fragment layout (bf16) ----------------
// dst[L][ks][nt][lane][j]: value = W_L[k = ks*32 + (lane>>4)*8 + j][col = nt*16 + (lane&15)]
// L=0..2 conv layers (nf|nc from W_pre_node, ef|ec from W_pre_edge), L=3 final (W_dist|W_const)
__global__ __launch_bounds__(256) void pack_w(const float* __restrict__ Wn,
    const float* __restrict__ We, const float* __restrict__ Wd,
    const float* __restrict__ Wc, unsigned short* __restrict__ dst)
{
    int idx = blockIdx.x*256 + threadIdx.x;
    if (idx >= 4*49152) return;
    int j    = idx & 7;
    int lane = (idx >> 3) & 63;
    int ntks = (idx >> 9) % 96;         // ks*16 + nt
    int L    = idx / 49152;
    int nt = ntks & 15, ks = ntks >> 4;
    int k   = ks*32 + (lane>>4)*8 + j;
    int col = nt*16 + (lane&15);
    float v = 0.f;
    if (k < ZZ) {
        if (L < 3) {
            if (col < 128)                     v = Wn[((size_t)L*ZZ + k)*128 + col];
            else if (col >= EFO && col < EFO+EE) v = We[((size_t)L*ZZ + k)*82 + (col-EFO)];
            else if (col >= ECO && col < ECO+EE) v = We[((size_t)L*ZZ + k)*82 + 41 + (col-ECO)];
        } else {
            if (col < 128) v = Wd[(size_t)k*128 + col];
            else           v = Wc[(size_t)k*128 + (col-128)];
        }
    }
    dst[idx] = f2bf(v);
}

// ---------------- distance ----------------
__global__ __launch_bounds__(256) void k_dist(const float* __restrict__ off,
    const float* __restrict__ apos, const float* __restrict__ cells,
    const int* __restrict__ eidx, float* __restrict__ distb)
{
    int idx = blockIdx.x*256 + threadIdx.x;
    if (idx >= NM) return;
    int n = idx / MM;
    const float* o  = off + (size_t)idx*3;
    const float* cl = cells + (size_t)n*9;
    int n2 = eidx[idx];
    float o0=o[0], o1=o[1], o2=o[2];
    float dd = 1e-12f;
    #pragma unroll
    for (int j=0;j<3;j++){
        float oc = o0*cl[0*3+j] + o1*cl[1*3+j] + o2*cl[2*3+j];
        float d = apos[(size_t)n2*3+j] + oc - apos[(size_t)n*3+j];
        dd += d*d;
    }
    distb[idx] = sqrtf(dd);
}

// ---------------- embedding: node0 = node_fea @ W_emb + b_emb ----------------
__global__ __launch_bounds__(256) void k_emb(const float* __restrict__ nf,
    const float* __restrict__ W, const float* __restrict__ b, float* __restrict__ node0)
{
    int idx = blockIdx.x*256 + threadIdx.x;
    if (idx >= NN*FF) return;
    int n = idx >> 6, c = idx & 63;
    float s = b[c];
    for (int k=0;k<OF;k++) s = fmaf(nf[(size_t)n*OF+k], W[k*FF+c], s);
    node0[idx] = s;
}

// ---------------- z staging into LDS: bf16 row-major [48][KP] ----------------
__device__ __forceinline__ void stage_z(unsigned short* __restrict__ Zl,
    const float* __restrict__ node_src, const float* __restrict__ edge_src,
    const int* __restrict__ eidx, int n0, int tid)
{
    const int gr0 = n0 * MM;
    for (int i = tid; i < RPB*48; i += 256) {
        int row = i / 48;
        int kq  = i - row*48;            // float4 index along k, 0..47 (k up to 191)
        float4 v = make_float4(0.f,0.f,0.f,0.f);
        int gr = gr0 + row;
        if (kq < 16) {                        // self node
            int n = n0 + row/MM;
            v = *(const float4*)(node_src + (size_t)n*FF + kq*4);
        } else if (kq < 32) {                 // neighbor node (gather)
            int n2 = eidx[gr];
            v = *(const float4*)(node_src + (size_t)n2*FF + (kq-16)*4);
        } else if (kq < 43) {                 // edge features (41 wide)
            int c0 = (kq - 32) * 4;
            const float* es = edge_src + (size_t)gr*EE;
            v.x = es[c0];
            if (c0+1 < EE) v.y = es[c0+1];
            if (c0+2 < EE) v.z = es[c0+2];
            if (c0+3 < EE) v.w = es[c0+3];
        }
        ushort4 u;
        u.x = f2bf(v.x); u.y = f2bf(v.y); u.z = f2bf(v.z); u.w = f2bf(v.w);
        *(ushort4*)(Zl + row*KP + kq*4) = u;
    }
}

// ---------------- MFMA core: 3 M-tiles x 4 col-group tiles per wave ----------------
// wave w owns N-tiles {w, w+4, w+8, w+12} -> col groups at {16w, 64+16w, 128+16w, 192+16w}
__device__ __forceinline__ void mfma_core(const unsigned short* __restrict__ Zl,
    const unsigned short* __restrict__ Wpk, int w, int lane, f32x4 (&acc)[3][4])
{
    const int quad = lane >> 4, li = lane & 15;
    #pragma unroll
    for (int mt=0;mt<3;mt++)
        #pragma unroll
        for (int t=0;t<4;t++) acc[mt][t] = (f32x4){0.f,0.f,0.f,0.f};

    for (int ks=0; ks<KSTEPS; ++ks) {
        bf16x8 bfr[4];
        #pragma unroll
        for (int t=0;t<4;t++){
            int nt = w + 4*t;
            bfr[t] = *(const bf16x8*)(Wpk + (((ks*16 + nt)*64 + lane) << 3));
        }
        bf16x8 afr[3];
        #pragma unroll
        for (int mt=0;mt<3;mt++){
            int row = mt*16 + li;
            afr[mt] = *(const bf16x8*)(Zl + row*KP + ks*32 + quad*8);
        }
        #pragma unroll
        for (int mt=0;mt<3;mt++)
            #pragma unroll
            for (int t=0;t<4;t++)
                acc[mt][t] = __builtin_amdgcn_mfma_f32_16x16x32_bf16(afr[mt], bfr[t], acc[mt][t], 0, 0, 0);
    }
}

// ---------------- stats pass: per-channel sum & sumsq of z@W ----------------
__global__ __launch_bounds__(256,2) void k_stats(
    const float* __restrict__ node_src, const float* __restrict__ edge_src,
    const int* __restrict__ eidx, const unsigned short* __restrict__ Wpk,
    float* __restrict__ sumv, float* __restrict__ sumq)
{
    __shared__ unsigned short Zl[RPB*KP];
    const int tid = threadIdx.x, w = tid>>6, lane = tid&63;
    const int n0 = blockIdx.x * NPB;
    stage_z(Zl, node_src, edge_src, eidx, n0, tid);
    __syncthreads();
    f32x4 acc[3][4];
    mfma_core(Zl, Wpk, w, lane, acc);
    const int quad = lane>>4, li = lane&15;
    #pragma unroll
    for (int t=0;t<4;t++){
        float s=0.f, q=0.f;
        #pragma unroll
        for (int mt=0;mt<3;mt++)
            #pragma unroll
            for (int r=0;r<4;r++){ float v = acc[mt][t][r]; s+=v; q+=v*v; }
        s += __shfl_xor(s,16); s += __shfl_xor(s,32);
        q += __shfl_xor(q,16); q += __shfl_xor(q,32);
        if (quad == 0) {
            int col = t*64 + w*16 + li;
            atomicAdd(&sumv[col], s);
            atomicAdd(&sumq[col], q);
        }
    }
}

// ---------------- finalize: mean / invstd ----------------
__global__ __launch_bounds__(256) void k_fin(const float* __restrict__ s,
    const float* __restrict__ q, float* __restrict__ m, float* __restrict__ istd,
    float inv_cnt, int ncols)
{
    int t = threadIdx.x;
    if (t < ncols) {
        float mm = s[t]*inv_cnt;
        float v  = q[t]*inv_cnt - mm*mm;
        m[t] = mm;
        istd[t] = rsqrtf(v + 1e-5f);
    }
}

// ---------------- apply pass: BN + gates, node aggr + edge g + their stats ----------------
__global__ __launch_bounds__(256,2) void k_apply(
    const float* __restrict__ node_src, const float* __restrict__ edge_src,
    const int* __restrict__ eidx, const unsigned short* __restrict__ Wpk,
    const float* __restrict__ mPre, const float* __restrict__ iPre,
    float* __restrict__ aggr, float* __restrict__ gbuf,
    float* __restrict__ aS, float* __restrict__ aQ,
    float* __restrict__ gS, float* __restrict__ gQ)
{
    __shared__ __align__(16) char smem[RPB*KP*2];
    unsigned short* Zl = (unsigned short*)smem;
    float* gL = (float*)smem;                 // 48*64 fp32 = 12288 B, aliases Zl (after sync)
    const int tid = threadIdx.x, w = tid>>6, lane = tid&63;
    const int n0 = blockIdx.x * NPB;
    const int gr0 = n0 * MM;
    stage_z(Zl, node_src, edge_src, eidx, n0, tid);
    __syncthreads();
    f32x4 acc[3][4];
    mfma_core(Zl, Wpk, w, lane, acc);
    __syncthreads();                          // all waves done reading Zl -> gL may alias

    const int quad = lane>>4, li = lane&15;
    const int cg = w*16 + li;
    const float mn0 = mPre[cg],      in0 = iPre[cg];
    const float mn1 = mPre[64+cg],   in1 = iPre[64+cg];
    // node gates -> LDS
    #pragma unroll
    for (int mt=0;mt<3;mt++)
        #pragma unroll
        for (int r=0;r<4;r++){
            int row = mt*16 + quad*4 + r;
            float nf = (acc[mt][0][r] - mn0) * in0;
            float nc = (acc[mt][1][r] - mn1) * in1;
            gL[row*64 + cg] = sigm(nf) * lrelu(nc);
        }
    // edge gates -> global + stats
    float pg = 0.f, pq = 0.f;
    bool ce_ok = cg < EE;
    if (ce_ok) {
        const float me0 = mPre[EFO+cg], ie0 = iPre[EFO+cg];
        const float me1 = mPre[ECO+cg], ie1 = iPre[ECO+cg];
        #pragma unroll
        for (int mt=0;mt<3;mt++)
            #pragma unroll
            for (int r=0;r<4;r++){
                int row = mt*16 + quad*4 + r;
                float ef = (acc[mt][2][r] - me0) * ie0;
                float ec = (acc[mt][3][r] - me1) * ie1;
                float gv = sigm(ef)*lrelu(ec);
                gbuf[(size_t)(gr0+row)*EE + cg] = gv;
                pg += gv; pq += gv*gv;
            }
    }
    pg += __shfl_xor(pg,16); pg += __shfl_xor(pg,32);
    pq += __shfl_xor(pq,16); pq += __shfl_xor(pq,32);
    if (quad==0 && ce_ok){ atomicAdd(&gS[cg], pg); atomicAdd(&gQ[cg], pq); }

    __syncthreads();
    if (tid < 64) {
        float sA=0.f, sQ=0.f;
        #pragma unroll
        for (int nl=0; nl<NPB; nl++){
            float vsum = 0.f;
            #pragma unroll
            for (int jj=0;jj<MM;jj++) vsum += gL[(nl*MM+jj)*64 + tid];
            aggr[(size_t)(n0+nl)*64 + tid] = vsum;
            sA += vsum; sQ += vsum*vsum;
        }
        atomicAdd(&aS[tid], sA);
        atomicAdd(&aQ[tid], sQ);
    }
}

// ---------------- residual updates ----------------
__global__ __launch_bounds__(256) void k_upd_node(const float* __restrict__ cur,
    const float* __restrict__ aggr, const float* __restrict__ mA,
    const float* __restrict__ iA, float* __restrict__ nxt)
{
    int idx = blockIdx.x*256 + threadIdx.x;
    if (idx >= NN*FF) return;
    int c = idx & 63;
    float v = (aggr[idx] - mA[c]) * iA[c];
    nxt[idx] = lrelu(cur[idx] + v);
}

__global__ __launch_bounds__(256) void k_upd_edge(const float* __restrict__ esrc,
    const float* __restrict__ g, const float* __restrict__ mG,
    const float* __restrict__ iG, float* __restrict__ edst)
{
    int idx = blockIdx.x*256 + threadIdx.x;
    if (idx >= NM*EE) return;
    int c = idx % EE;
    float v = (g[idx] - mG[c]) * iG[c];
    edst[idx] = lrelu(esrc[idx] + v);
}

// ---------------- final heads ----------------
__global__ __launch_bounds__(256,2) void k_final(
    const float* __restrict__ node_src, const float* __restrict__ edge_src,
    const int* __restrict__ eidx, const unsigned short* __restrict__ Wpk,
    const float* __restrict__ mF, const float* __restrict__ iF,
    const float* __restrict__ distb, float* __restrict__ out)
{
    __shared__ __align__(16) char smem[2*RPB*64*4];   // 24576 B; Zl (19200) aliases front
    unsigned short* Zl = (unsigned short*)smem;
    float* bufD = (float*)smem;            // [48][64]
    float* bufC = (float*)smem + RPB*64;   // [48][64]
    const int tid = threadIdx.x, w = tid>>6, lane = tid&63;
    const int n0 = blockIdx.x * NPB;
    const int gr0 = n0 * MM;
    stage_z(Zl, node_src, edge_src, eidx, n0, tid);
    __syncthreads();
    f32x4 acc[3][4];
    mfma_core(Zl, Wpk, w, lane, acc);
    __syncthreads();                       // Zl dead -> bufD/C alias

    const int quad = lane>>4, li = lane&15;
    const int c = w*16 + li;
    const float m0=mF[c],     i0=iF[c];
    const float m1=mF[64+c],  i1=iF[64+c];
    const float m2=mF[128+c], i2=iF[128+c];
    const float m3=mF[192+c], i3=iF[192+c];
    #pragma unroll
    for (int mt=0;mt<3;mt++)
        #pragma unroll
        for (int r=0;r<4;r++){
            int row = mt*16 + quad*4 + r;
            float dv = distb[gr0 + row];
            float d0 = (acc[mt][0][r]-m0)*i0 + dv;
            float d1 = (acc[mt][1][r]-m1)*i1 + dv;
            float c0 = (acc[mt][2][r]-m2)*i2;
            float c1 = (acc[mt][3][r]-m3)*i3;
            bufD[row*64 + c] = softpl(d0)+softpl(d1);
            bufC[row*64 + c] = softpl(c0)+softpl(c1);
        }
    __syncthreads();
    if (tid < RPB) {
        float sd=0.f, sc=0.f;
        #pragma unroll 8
        for (int t=0;t<64;t++){ sd += bufD[tid*64+t]; sc += bufC[tid*64+t]; }
        size_t gr = gr0 + tid;
        out[gr*2+0] = sd * (1.f/128.f);
        out[gr*2+1] = sc * (1.f/128.f) * (1.f/(float)NN);
    }
}

// ---------------- launch ----------------
extern "C" void kernel_launch(void* const* d_in, const int* in_sizes, int n_in,
                              void* d_out, int out_size, void* d_ws, size_t ws_size,
                              hipStream_t stream)
{
    const float* node_fea = (const float*)d_in[0];
    const float* edge_in  = (const float*)d_in[1];
    const float* nbr_off  = (const float*)d_in[2];
    const float* apos     = (const float*)d_in[3];
    const float* cells    = (const float*)d_in[4];
    const int*   eidx     = (const int*)  d_in[5];
    const float* W_emb    = (const float*)d_in[6];
    const float* b_emb    = (const float*)d_in[7];
    const float* W_pn     = (const float*)d_in[8];
    const float* W_pe     = (const float*)d_in[10];
    const float* W_dist   = (const float*)d_in[12];
    const float* W_cst    = (const float*)d_in[14];
    float* out = (float*)d_out;
    float* wsf = (float*)d_ws;

    size_t o = 0;
    float* node0 = wsf + o; o += (size_t)NN*FF;
    float* node1 = wsf + o; o += (size_t)NN*FF;
    float* edgew = wsf + o; o += (size_t)NM*EE;
    float* gbuf  = wsf + o; o += (size_t)NM*EE;
    float* aggr  = wsf + o; o += (size_t)NN*FF;
    float* distb = wsf + o; o += (size_t)NM;
    float* stats = wsf + o; o += 4096;
    float* msb   = wsf + o; o += 4096;
    unsigned short* Wpk = (unsigned short*)(wsf + o);   // 4*49152 bf16 = 384 KB

    hipMemsetAsync(stats, 0, 4096*sizeof(float), stream);
    pack_w<<<(4*49152+255)/256, 256, 0, stream>>>(W_pn, W_pe, W_dist, W_cst, Wpk);
    k_dist <<<(NM+255)/256,     256, 0, stream>>>(nbr_off, apos, cells, eidx, distb);
    k_emb  <<<(NN*FF+255)/256,  256, 0, stream>>>(node_fea, W_emb, b_emb, node0);

    const float invNM = 1.f/(float)NM, invN = 1.f/(float)NN;
    const float* ncur = node0;
    const float* ecur = edge_in;

    for (int l=0;l<3;l++){
        float* st = stats + l*768;
        float* ms = msb   + l*768;
        float* preS = st;       float* preQ = st+256;
        float* aS   = st+512;   float* aQ   = st+576;
        float* gS   = st+640;   float* gQ   = st+704;
        float* mPre = ms;       float* iPre = ms+256;
        float* mA   = ms+512;   float* iA   = ms+576;
        float* mG   = ms+640;   float* iG   = ms+704;
        const unsigned short* Wl = Wpk + (size_t)l*49152;
        float* ndst = (l & 1) ? node0 : node1;

        k_stats<<<NBLK,256,0,stream>>>(ncur, ecur, eidx, Wl, preS, preQ);
        k_fin  <<<1,256,0,stream>>>(preS, preQ, mPre, iPre, invNM, 256);
        k_apply<<<NBLK,256,0,stream>>>(ncur, ecur, eidx, Wl, mPre, iPre,
                                       aggr, gbuf, aS, aQ, gS, gQ);
        k_fin  <<<1,256,0,stream>>>(aS, aQ, mA, iA, invN, 64);
        k_fin  <<<1,256,0,stream>>>(gS, gQ, mG, iG, invNM, EE);
        k_upd_node<<<(NN*FF+255)/256,256,0,stream>>>(ncur, aggr, mA, iA, ndst);
        k_upd_edge<<<(NM*EE+255)/256,256,0,stream>>>(ecur, gbuf, mG, iG, edgew);
        ncur = ndst;
        ecur = edgew;
    }

    float* fS = stats + 3*768; float* fQ = fS + 256;
    float* mF = msb   + 3*768; float* iF = mF + 256;
    k_stats<<<NBLK,256,0,stream>>>(ncur, ecur, eidx, Wpk + (size_t)3*49152, fS, fQ);
    k_fin  <<<1,256,0,stream>>>(fS, fQ, mF, iF, invNM, 256);
    k_final<<<NBLK,256,0,stream>>>(ncur, ecur, eidx, Wpk + (size_t)3*49152, mF, iF, distb, out);
}

// Round 3
// 3101.473 us; speedup vs baseline: 2.6697x; 1.0914x over previous
//
#include <hip/hip_runtime.h>
#include <math.h>

// ---------------- problem constants ----------------
#define NN 50000      // nodes
#define MM 12         // neighbors
#define NM 600000     // edges = NN*MM
#define OF 92         // orig node features
#define FF 64         // node feature dim
#define EE 41         // edge feature dim
#define ES 48         // padded edge stride (bf16), cols 41..47 = 0
#define ZZ 169        // 2*FF + EE
#define EFO 128
#define ECO 192
#define RPB 48        // rows (edges) per block = 4 nodes * 12
#define NPB 4         // nodes per block
#define NBLK 12500    // NN / NPB
#define KP 200        // padded K stride (bf16 elements) in LDS
#define KSTEPS 6      // 6 * 32 = 192 >= 169

typedef __bf16 bf16x8 __attribute__((ext_vector_type(8)));
typedef float  f32x4  __attribute__((ext_vector_type(4)));

__device__ __forceinline__ float lrelu(float x){ return x > 0.f ? x : 0.01f*x; }
__device__ __forceinline__ float sigm(float x){ return __builtin_amdgcn_rcpf(1.f+__expf(-x)); }
__device__ __forceinline__ float softpl(float x){ return fmaxf(x,0.f) + log1pf(__expf(-fabsf(x))); }
__device__ __forceinline__ unsigned short f2bf(float f){
    __bf16 h = (__bf16)f;
    return __builtin_bit_cast(unsigned short, h);
}
__device__ __forceinline__ float b2f(unsigned short u){
    unsigned int b = ((unsigned int)u) << 16;
    return __builtin_bit_cast(float, b);
}

// ---------------- weight packing into B-fragment layout (bf16) ----------------
// dst[L][ks][nt][lane][j]: value = W_L[k = ks*32 + (lane>>4)*8 + j][col = nt*16 + (lane&15)]
__global__ __launch_bounds__(256) void pack_w(const float* __restrict__ Wn,
    const float* __restrict__ We, const float* __restrict__ Wd,
    const float* __restrict__ Wc, unsigned short* __restrict__ dst)
{
    int idx = blockIdx.x*256 + threadIdx.x;
    if (idx >= 4*49152) return;
    int j    = idx & 7;
    int lane = (idx >> 3) & 63;
    int ntks = (idx >> 9) % 96;         // ks*16 + nt
    int L    = idx / 49152;
    int nt = ntks & 15, ks = ntks >> 4;
    int k   = ks*32 + (lane>>4)*8 + j;
    int col = nt*16 + (lane&15);
    float v = 0.f;
    if (k < ZZ) {
        if (L < 3) {
            if (col < 128)                       v = Wn[((size_t)L*ZZ + k)*128 + col];
            else if (col >= EFO && col < EFO+EE) v = We[((size_t)L*ZZ + k)*82 + (col-EFO)];
            else if (col >= ECO && col < ECO+EE) v = We[((size_t)L*ZZ + k)*82 + 41 + (col-ECO)];
        } else {
            if (col < 128) v = Wd[(size_t)k*128 + col];
            else           v = Wc[(size_t)k*128 + (col-128)];
        }
    }
    dst[idx] = f2bf(v);
}

// ---------------- distance ----------------
__global__ __launch_bounds__(256) void k_dist(const float* __restrict__ off,
    const float* __restrict__ apos, const float* __restrict__ cells,
    const int* __restrict__ eidx, float* __restrict__ distb)
{
    int idx = blockIdx.x*256 + threadIdx.x;
    if (idx >= NM) return;
    int n = idx / MM;
    const float* o  = off + (size_t)idx*3;
    const float* cl = cells + (size_t)n*9;
    int n2 = eidx[idx];
    float o0=o[0], o1=o[1], o2=o[2];
    float dd = 1e-12f;
    #pragma unroll
    for (int j=0;j<3;j++){
        float oc = o0*cl[0*3+j] + o1*cl[1*3+j] + o2*cl[2*3+j];
        float d = apos[(size_t)n2*3+j] + oc - apos[(size_t)n*3+j];
        dd += d*d;
    }
    distb[idx] = sqrtf(dd);
}

// ---------------- edge convert: fp32 [NM][41] -> bf16 [NM][48] (pad 0) ----------------
__global__ __launch_bounds__(256) void k_cvt(const float* __restrict__ src,
    unsigned short* __restrict__ e)
{
    int gr = blockIdx.x*256 + threadIdx.x;
    if (gr >= NM) return;
    const float* s = src + (size_t)gr*EE;
    unsigned short* d = e + (size_t)gr*ES;
    #pragma unroll
    for (int c=0;c<EE;c++) d[c] = f2bf(s[c]);
    #pragma unroll
    for (int c=EE;c<ES;c++) d[c] = 0;
}

// ---------------- embedding: node0 = bf16(node_fea @ W_emb + b_emb) ----------------
__global__ __launch_bounds__(256) void k_emb(const float* __restrict__ nf,
    const float* __restrict__ W, const float* __restrict__ b,
    unsigned short* __restrict__ node0)
{
    int idx = blockIdx.x*256 + threadIdx.x;
    if (idx >= NN*FF) return;
    int n = idx >> 6, c = idx & 63;
    float s = b[c];
    for (int k=0;k<OF;k++) s = fmaf(nf[(size_t)n*OF+k], W[k*FF+c], s);
    node0[idx] = f2bf(s);
}

// ---------------- z staging into LDS: bf16 [48][KP], pure 16B copies ----------------
// row chunks (16B each): ch 0..7 self node, 8..15 neighbor node, 16..21 edge, 22..23 zero
__device__ __forceinline__ void stage_z(unsigned short* __restrict__ Zl,
    const unsigned short* __restrict__ node_src, const unsigned short* __restrict__ edge_src,
    const int* __restrict__ eidx, int n0, int tid)
{
    const int gr0 = n0 * MM;
    for (int i = tid; i < RPB*24; i += 256) {
        int row = i / 24;
        int ch  = i - row*24;
        int gr  = gr0 + row;
        uint4 v = make_uint4(0u,0u,0u,0u);
        if (ch < 8) {
            int n = n0 + row/MM;
            v = *(const uint4*)(node_src + (size_t)n*FF + ch*8);
        } else if (ch < 16) {
            int n2 = eidx[gr];
            v = *(const uint4*)(node_src + (size_t)n2*FF + (ch-8)*8);
        } else if (ch < 22) {
            v = *(const uint4*)(edge_src + (size_t)gr*ES + (ch-16)*8);
        }
        *(uint4*)(Zl + row*KP + ch*8) = v;
    }
}

// ---------------- MFMA core: 3 M-tiles x 4 col-group tiles per wave ----------------
__device__ __forceinline__ void mfma_core(const unsigned short* __restrict__ Zl,
    const unsigned short* __restrict__ Wpk, int w, int lane, f32x4 (&acc)[3][4])
{
    const int quad = lane >> 4, li = lane & 15;
    #pragma unroll
    for (int mt=0;mt<3;mt++)
        #pragma unroll
        for (int t=0;t<4;t++) acc[mt][t] = (f32x4){0.f,0.f,0.f,0.f};

    for (int ks=0; ks<KSTEPS; ++ks) {
        bf16x8 bfr[4];
        #pragma unroll
        for (int t=0;t<4;t++){
            int nt = w + 4*t;
            bfr[t] = *(const bf16x8*)(Wpk + (((ks*16 + nt)*64 + lane) << 3));
        }
        bf16x8 afr[3];
        #pragma unroll
        for (int mt=0;mt<3;mt++){
            int row = mt*16 + li;
            afr[mt] = *(const bf16x8*)(Zl + row*KP + ks*32 + quad*8);
        }
        #pragma unroll
        for (int mt=0;mt<3;mt++)
            #pragma unroll
            for (int t=0;t<4;t++)
                acc[mt][t] = __builtin_amdgcn_mfma_f32_16x16x32_bf16(afr[mt], bfr[t], acc[mt][t], 0, 0, 0);
    }
}

// ---------------- stats pass: per-channel sum & sumsq of z@W ----------------
__global__ __launch_bounds__(256) void k_stats(
    const unsigned short* __restrict__ node_src, const unsigned short* __restrict__ edge_src,
    const int* __restrict__ eidx, const unsigned short* __restrict__ Wpk,
    float* __restrict__ sumv, float* __restrict__ sumq)
{
    __shared__ unsigned short Zl[RPB*KP];
    const int tid = threadIdx.x, w = tid>>6, lane = tid&63;
    const int n0 = blockIdx.x * NPB;
    stage_z(Zl, node_src, edge_src, eidx, n0, tid);
    __syncthreads();
    f32x4 acc[3][4];
    mfma_core(Zl, Wpk, w, lane, acc);
    const int quad = lane>>4, li = lane&15;
    #pragma unroll
    for (int t=0;t<4;t++){
        float s=0.f, q=0.f;
        #pragma unroll
        for (int mt=0;mt<3;mt++)
            #pragma unroll
            for (int r=0;r<4;r++){ float v = acc[mt][t][r]; s+=v; q+=v*v; }
        s += __shfl_xor(s,16); s += __shfl_xor(s,32);
        q += __shfl_xor(q,16); q += __shfl_xor(q,32);
        if (quad == 0) {
            int col = t*64 + w*16 + li;
            atomicAdd(&sumv[col], s);
            atomicAdd(&sumq[col], q);
        }
    }
}

// ---------------- finalize: mean / invstd ----------------
__global__ __launch_bounds__(256) void k_fin(const float* __restrict__ s,
    const float* __restrict__ q, float* __restrict__ m, float* __restrict__ istd,
    float inv_cnt, int ncols)
{
    int t = threadIdx.x;
    if (t < ncols) {
        float mm = s[t]*inv_cnt;
        float v  = q[t]*inv_cnt - mm*mm;
        m[t] = mm;
        istd[t] = rsqrtf(v + 1e-5f);
    }
}

// combined finalize: aggr stats (64, invN) + g stats (41, invNM)
__global__ __launch_bounds__(128) void k_fin2(
    const float* __restrict__ aS, const float* __restrict__ aQ,
    float* __restrict__ mA, float* __restrict__ iA,
    const float* __restrict__ gS, const float* __restrict__ gQ,
    float* __restrict__ mG, float* __restrict__ iG)
{
    int t = threadIdx.x;
    if (t < 64) {
        float mm = aS[t]*(1.f/(float)NN);
        float v  = aQ[t]*(1.f/(float)NN) - mm*mm;
        mA[t] = mm; iA[t] = rsqrtf(v + 1e-5f);
    } else if (t < 64+EE) {
        int c = t-64;
        float mm = gS[c]*(1.f/(float)NM);
        float v  = gQ[c]*(1.f/(float)NM) - mm*mm;
        mG[c] = mm; iG[c] = rsqrtf(v + 1e-5f);
    }
}

// ---------------- apply pass: BN + gates, node aggr + edge g + their stats ----------------
__global__ __launch_bounds__(256) void k_apply(
    const unsigned short* __restrict__ node_src, const unsigned short* __restrict__ edge_src,
    const int* __restrict__ eidx, const unsigned short* __restrict__ Wpk,
    const float* __restrict__ mPre, const float* __restrict__ iPre,
    float* __restrict__ aggr, unsigned short* __restrict__ gbuf,
    float* __restrict__ aS, float* __restrict__ aQ,
    float* __restrict__ gS, float* __restrict__ gQ)
{
    __shared__ __align__(16) char smem[RPB*KP*2];   // 19200 B; Zl then aliased by gL (12288 B)
    unsigned short* Zl = (unsigned short*)smem;
    float* gL = (float*)smem;
    const int tid = threadIdx.x, w = tid>>6, lane = tid&63;
    const int n0 = blockIdx.x * NPB;
    const int gr0 = n0 * MM;
    stage_z(Zl, node_src, edge_src, eidx, n0, tid);
    __syncthreads();
    f32x4 acc[3][4];
    mfma_core(Zl, Wpk, w, lane, acc);
    __syncthreads();                          // all waves done reading Zl -> gL may alias

    const int quad = lane>>4, li = lane&15;
    const int cg = w*16 + li;
    const float mn0 = mPre[cg],      in0 = iPre[cg];
    const float mn1 = mPre[64+cg],   in1 = iPre[64+cg];
    // node gates -> LDS
    #pragma unroll
    for (int mt=0;mt<3;mt++)
        #pragma unroll
        for (int r=0;r<4;r++){
            int row = mt*16 + quad*4 + r;
            float nf = (acc[mt][0][r] - mn0) * in0;
            float nc = (acc[mt][1][r] - mn1) * in1;
            gL[row*64 + cg] = sigm(nf) * lrelu(nc);
        }
    // edge gates -> global (bf16) + stats
    float pg = 0.f, pq = 0.f;
    bool ce_ok = cg < EE;
    if (ce_ok) {
        const float me0 = mPre[EFO+cg], ie0 = iPre[EFO+cg];
        const float me1 = mPre[ECO+cg], ie1 = iPre[ECO+cg];
        #pragma unroll
        for (int mt=0;mt<3;mt++)
            #pragma unroll
            for (int r=0;r<4;r++){
                int row = mt*16 + quad*4 + r;
                float ef = (acc[mt][2][r] - me0) * ie0;
                float ec = (acc[mt][3][r] - me1) * ie1;
                float gv = sigm(ef)*lrelu(ec);
                gbuf[(size_t)(gr0+row)*EE + cg] = f2bf(gv);
                pg += gv; pq += gv*gv;
            }
    }
    pg += __shfl_xor(pg,16); pg += __shfl_xor(pg,32);
    pq += __shfl_xor(pq,16); pq += __shfl_xor(pq,32);
    if (quad==0 && ce_ok){ atomicAdd(&gS[cg], pg); atomicAdd(&gQ[cg], pq); }

    __syncthreads();
    if (tid < 64) {
        float sA=0.f, sQ=0.f;
        #pragma unroll
        for (int nl=0; nl<NPB; nl++){
            float vsum = 0.f;
            #pragma unroll
            for (int jj=0;jj<MM;jj++) vsum += gL[(nl*MM+jj)*64 + tid];
            aggr[(size_t)(n0+nl)*64 + tid] = vsum;
            sA += vsum; sQ += vsum*vsum;
        }
        atomicAdd(&aS[tid], sA);
        atomicAdd(&aQ[tid], sQ);
    }
}

// ---------------- residual updates ----------------
__global__ __launch_bounds__(256) void k_upd_node(const unsigned short* __restrict__ cur,
    const float* __restrict__ aggr, const float* __restrict__ mA,
    const float* __restrict__ iA, unsigned short* __restrict__ nxt)
{
    int idx = blockIdx.x*256 + threadIdx.x;
    if (idx >= NN*FF) return;
    int c = idx & 63;
    float v = (aggr[idx] - mA[c]) * iA[c];
    nxt[idx] = f2bf(lrelu(b2f(cur[idx]) + v));
}

// edge update in place: e[gr][ce] = lrelu(e + BN(g)), pad cols untouched (stay 0)
__global__ __launch_bounds__(256) void k_upd_edge(unsigned short* __restrict__ e,
    const unsigned short* __restrict__ g, const float* __restrict__ mG,
    const float* __restrict__ iG)
{
    int gr = blockIdx.x*256 + threadIdx.x;
    if (gr >= NM) return;
    unsigned short* er = e + (size_t)gr*ES;
    const unsigned short* grow = g + (size_t)gr*EE;
    #pragma unroll
    for (int c=0;c<EE;c++){
        float v = (b2f(grow[c]) - mG[c]) * iG[c];
        er[c] = f2bf(lrelu(b2f(er[c]) + v));
    }
}

// ---------------- final heads ----------------
__global__ __launch_bounds__(256) void k_final(
    const unsigned short* __restrict__ node_src, const unsigned short* __restrict__ edge_src,
    const int* __restrict__ eidx, const unsigned short* __restrict__ Wpk,
    const float* __restrict__ mF, const float* __restrict__ iF,
    const float* __restrict__ distb, float* __restrict__ out)
{
    __shared__ unsigned short Zl[RPB*KP];
    __shared__ float redD[RPB*4];
    __shared__ float redC[RPB*4];
    const int tid = threadIdx.x, w = tid>>6, lane = tid&63;
    const int n0 = blockIdx.x * NPB;
    const int gr0 = n0 * MM;
    stage_z(Zl, node_src, edge_src, eidx, n0, tid);
    __syncthreads();
    f32x4 acc[3][4];
    mfma_core(Zl, Wpk, w, lane, acc);

    const int quad = lane>>4, li = lane&15;
    const int c = w*16 + li;
    const float m0=mF[c],     i0=iF[c];
    const float m1=mF[64+c],  i1=iF[64+c];
    const float m2=mF[128+c], i2=iF[128+c];
    const float m3=mF[192+c], i3=iF[192+c];
    #pragma unroll
    for (int mt=0;mt<3;mt++)
        #pragma unroll
        for (int r=0;r<4;r++){
            int row = mt*16 + quad*4 + r;
            float dv = distb[gr0 + row];
            float pd = softpl((acc[mt][0][r]-m0)*i0 + dv)
                     + softpl((acc[mt][1][r]-m1)*i1 + dv);
            float pc = softpl((acc[mt][2][r]-m2)*i2)
                     + softpl((acc[mt][3][r]-m3)*i3);
            // reduce over li within the 16-lane group
            pd += __shfl_xor(pd,1); pd += __shfl_xor(pd,2);
            pd += __shfl_xor(pd,4); pd += __shfl_xor(pd,8);
            pc += __shfl_xor(pc,1); pc += __shfl_xor(pc,2);
            pc += __shfl_xor(pc,4); pc += __shfl_xor(pc,8);
            if (li == 0) {
                redD[row*4 + w] = pd;
                redC[row*4 + w] = pc;
            }
        }
    __syncthreads();
    if (tid < RPB) {
        float sd = redD[tid*4+0]+redD[tid*4+1]+redD[tid*4+2]+redD[tid*4+3];
        float sc = redC[tid*4+0]+redC[tid*4+1]+redC[tid*4+2]+redC[tid*4+3];
        size_t gr = gr0 + tid;
        out[gr*2+0] = sd * (1.f/128.f);
        out[gr*2+1] = sc * (1.f/128.f) * (1.f/(float)NN);
    }
}

// ---------------- launch ----------------
extern "C" void kernel_launch(void* const* d_in, const int* in_sizes, int n_in,
                              void* d_out, int out_size, void* d_ws, size_t ws_size,
                              hipStream_t stream)
{
    const float* node_fea = (const float*)d_in[0];
    const float* edge_in  = (const float*)d_in[1];
    const float* nbr_off  = (const float*)d_in[2];
    const float* apos     = (const float*)d_in[3];
    const float* cells    = (const float*)d_in[4];
    const int*   eidx     = (const int*)  d_in[5];
    const float* W_emb    = (const float*)d_in[6];
    const float* b_emb    = (const float*)d_in[7];
    const float* W_pn     = (const float*)d_in[8];
    const float* W_pe     = (const float*)d_in[10];
    const float* W_dist   = (const float*)d_in[12];
    const float* W_cst    = (const float*)d_in[14];
    float* out = (float*)d_out;
    char* ws = (char*)d_ws;

    size_t o = 0;
    auto alloc = [&](size_t bytes) { char* p = ws + o; o += (bytes + 255) & ~(size_t)255; return p; };
    unsigned short* node0 = (unsigned short*)alloc((size_t)NN*FF*2);
    unsigned short* node1 = (unsigned short*)alloc((size_t)NN*FF*2);
    unsigned short* ebuf  = (unsigned short*)alloc((size_t)NM*ES*2);
    unsigned short* gbuf  = (unsigned short*)alloc((size_t)NM*EE*2);
    float* aggr  = (float*)alloc((size_t)NN*FF*4);
    float* distb = (float*)alloc((size_t)NM*4);
    unsigned short* Wpk = (unsigned short*)alloc((size_t)4*49152*2);
    float* stats = (float*)alloc(4096*4);
    float* msb   = (float*)alloc(4096*4);

    hipMemsetAsync(stats, 0, 4096*sizeof(float), stream);
    pack_w<<<(4*49152+255)/256, 256, 0, stream>>>(W_pn, W_pe, W_dist, W_cst, Wpk);
    k_dist <<<(NM+255)/256,     256, 0, stream>>>(nbr_off, apos, cells, eidx, distb);
    k_cvt  <<<(NM+255)/256,     256, 0, stream>>>(edge_in, ebuf);
    k_emb  <<<(NN*FF+255)/256,  256, 0, stream>>>(node_fea, W_emb, b_emb, node0);

    const float invNM = 1.f/(float)NM;
    const unsigned short* ncur = node0;

    for (int l=0;l<3;l++){
        float* st = stats + l*768;
        float* ms = msb   + l*768;
        float* preS = st;       float* preQ = st+256;
        float* aS   = st+512;   float* aQ   = st+576;
        float* gS   = st+640;   float* gQ   = st+704;
        float* mPre = ms;       float* iPre = ms+256;
        float* mA   = ms+512;   float* iA   = ms+576;
        float* mG   = ms+640;   float* iG   = ms+704;
        const unsigned short* Wl = Wpk + (size_t)l*49152;
        unsigned short* ndst = (l & 1) ? node0 : node1;

        k_stats<<<NBLK,256,0,stream>>>(ncur, ebuf, eidx, Wl, preS, preQ);
        k_fin  <<<1,256,0,stream>>>(preS, preQ, mPre, iPre, invNM, 256);
        k_apply<<<NBLK,256,0,stream>>>(ncur, ebuf, eidx, Wl, mPre, iPre,
                                       aggr, gbuf, aS, aQ, gS, gQ);
        k_fin2 <<<1,128,0,stream>>>(aS, aQ, mA, iA, gS, gQ, mG, iG);
        k_upd_node<<<(NN*FF+255)/256,256,0,stream>>>(ncur, aggr, mA, iA, ndst);
        k_upd_edge<<<(NM+255)/256,256,0,stream>>>(ebuf, gbuf, mG, iG);
        ncur = ndst;
    }

    float* fS = stats + 3*768; float* fQ = fS + 256;
    float* mF = msb   + 3*768; float* iF = mF + 256;
    k_stats<<<NBLK,256,0,stream>>>(ncur, ebuf, eidx, Wpk + (size_t)3*49152, fS, fQ);
    k_fin  <<<1,256,0,stream>>>(fS, fQ, mF, iF, invNM, 256);
    k_final<<<NBLK,256,0,stream>>>(ncur, ebuf, eidx, Wpk + (size_t)3*49152, mF, iF, distb, out);
}

// Round 4
// 2102.540 us; speedup vs baseline: 3.9380x; 1.4751x over previous
//
#include <hip/hip_runtime.h>
#include <math.h>

// ---------------- problem constants ----------------
#define NN 50000      // nodes
#define MM 12         // neighbors
#define NM 600000     // edges = NN*MM
#define OF 92         // orig node features
#define FF 64         // node feature dim
#define EE 41         // edge feature dim
#define ES 48         // padded edge stride (bf16), cols 41..47 = 0
#define ZZ 169        // 2*FF + EE
#define EFO 128
#define ECO 192
#define RPB 96        // rows (edges) per block = 8 nodes * 12
#define NPB 8         // nodes per block
#define NBLK 6250     // NN / NPB
#define KP 200        // padded K stride (bf16 elements) in LDS
#define KSTEPS 6      // 6 * 32 = 192 >= 169
#define MT 6          // M-tiles per block (96/16)

typedef __bf16 bf16x8 __attribute__((ext_vector_type(8)));
typedef float  f32x4  __attribute__((ext_vector_type(4)));

__device__ __forceinline__ float lrelu(float x){ return fmaxf(x, 0.01f*x); }
__device__ __forceinline__ float sigm(float x){ return __builtin_amdgcn_rcpf(1.f+__expf(-x)); }
__device__ __forceinline__ float softpl(float x){ return fmaxf(x,0.f) + __logf(1.f+__expf(-fabsf(x))); }
__device__ __forceinline__ unsigned short f2bf(float f){
    __bf16 h = (__bf16)f;
    return __builtin_bit_cast(unsigned short, h);
}
__device__ __forceinline__ float b2f(unsigned short u){
    unsigned int b = ((unsigned int)u) << 16;
    return __builtin_bit_cast(float, b);
}

// ---------------- weight packing into B-fragment layout (bf16) ----------------
// dst[L][ks][nt][lane][j]: value = W_L[k = ks*32 + (lane>>4)*8 + j][col = nt*16 + (lane&15)]
__global__ __launch_bounds__(256) void pack_w(const float* __restrict__ Wn,
    const float* __restrict__ We, const float* __restrict__ Wd,
    const float* __restrict__ Wc, unsigned short* __restrict__ dst)
{
    int idx = blockIdx.x*256 + threadIdx.x;
    if (idx >= 4*49152) return;
    int j    = idx & 7;
    int lane = (idx >> 3) & 63;
    int ntks = (idx >> 9) % 96;         // ks*16 + nt
    int L    = idx / 49152;
    int nt = ntks & 15, ks = ntks >> 4;
    int k   = ks*32 + (lane>>4)*8 + j;
    int col = nt*16 + (lane&15);
    float v = 0.f;
    if (k < ZZ) {
        if (L < 3) {
            if (col < 128)                       v = Wn[((size_t)L*ZZ + k)*128 + col];
            else if (col >= EFO && col < EFO+EE) v = We[((size_t)L*ZZ + k)*82 + (col-EFO)];
            else if (col >= ECO && col < ECO+EE) v = We[((size_t)L*ZZ + k)*82 + 41 + (col-ECO)];
        } else {
            if (col < 128) v = Wd[(size_t)k*128 + col];
            else           v = Wc[(size_t)k*128 + (col-128)];
        }
    }
    dst[idx] = f2bf(v);
}

// ---------------- distance ----------------
__global__ __launch_bounds__(256) void k_dist(const float* __restrict__ off,
    const float* __restrict__ apos, const float* __restrict__ cells,
    const int* __restrict__ eidx, float* __restrict__ distb)
{
    int idx = blockIdx.x*256 + threadIdx.x;
    if (idx >= NM) return;
    int n = idx / MM;
    const float* o  = off + (size_t)idx*3;
    const float* cl = cells + (size_t)n*9;
    int n2 = eidx[idx];
    float o0=o[0], o1=o[1], o2=o[2];
    float dd = 1e-12f;
    #pragma unroll
    for (int j=0;j<3;j++){
        float oc = o0*cl[0*3+j] + o1*cl[1*3+j] + o2*cl[2*3+j];
        float d = apos[(size_t)n2*3+j] + oc - apos[(size_t)n*3+j];
        dd += d*d;
    }
    distb[idx] = sqrtf(dd);
}

// ---------------- edge convert: fp32 [NM][41] -> bf16 [NM][48] (pad 0), coalesced ----------------
__global__ __launch_bounds__(256) void k_cvt(const float* __restrict__ src,
    unsigned short* __restrict__ e)
{
    int idx = blockIdx.x*256 + threadIdx.x;
    if (idx >= NM*ES) return;
    int gr = idx / ES;
    int c  = idx - gr*ES;
    e[idx] = (c < EE) ? f2bf(src[(size_t)gr*EE + c]) : (unsigned short)0;
}

// ---------------- embedding: node0 = bf16(node_fea @ W_emb + b_emb) ----------------
__global__ __launch_bounds__(256) void k_emb(const float* __restrict__ nf,
    const float* __restrict__ W, const float* __restrict__ b,
    unsigned short* __restrict__ node0)
{
    int idx = blockIdx.x*256 + threadIdx.x;
    if (idx >= NN*FF) return;
    int n = idx >> 6, c = idx & 63;
    float s = b[c];
    for (int k=0;k<OF;k++) s = fmaf(nf[(size_t)n*OF+k], W[k*FF+c], s);
    node0[idx] = f2bf(s);
}

// ---------------- z staging into LDS: bf16 [96][KP], pure 16B copies ----------------
// row chunks (16B each): ch 0..7 self node, 8..15 neighbor node, 16..21 edge, 22..23 zero
__device__ __forceinline__ void stage_z(unsigned short* __restrict__ Zl,
    const unsigned short* __restrict__ node_src, const unsigned short* __restrict__ edge_src,
    const int* __restrict__ eidx, int n0, int tid)
{
    const int gr0 = n0 * MM;
    #pragma unroll
    for (int it = 0; it < (RPB*24)/256; ++it) {
        int i = it*256 + tid;
        int row = i / 24;
        int ch  = i - row*24;
        int gr  = gr0 + row;
        uint4 v = make_uint4(0u,0u,0u,0u);
        if (ch < 8) {
            int n = n0 + row/MM;
            v = *(const uint4*)(node_src + (size_t)n*FF + ch*8);
        } else if (ch < 16) {
            int n2 = eidx[gr];
            v = *(const uint4*)(node_src + (size_t)n2*FF + (ch-8)*8);
        } else if (ch < 22) {
            v = *(const uint4*)(edge_src + (size_t)gr*ES + (ch-16)*8);
        }
        *(uint4*)(Zl + row*KP + ch*8) = v;
    }
}

// ---------------- MFMA core: 6 M-tiles x 4 col-group tiles per wave ----------------
__device__ __forceinline__ void mfma_core(const unsigned short* __restrict__ Zl,
    const unsigned short* __restrict__ Wpk, int w, int lane, f32x4 (&acc)[MT][4])
{
    const int quad = lane >> 4, li = lane & 15;
    #pragma unroll
    for (int mt=0;mt<MT;mt++)
        #pragma unroll
        for (int t=0;t<4;t++) acc[mt][t] = (f32x4){0.f,0.f,0.f,0.f};

    #pragma unroll 2
    for (int ks=0; ks<KSTEPS; ++ks) {
        bf16x8 bfr[4];
        #pragma unroll
        for (int t=0;t<4;t++){
            int nt = w + 4*t;
            bfr[t] = *(const bf16x8*)(Wpk + (((ks*16 + nt)*64 + lane) << 3));
        }
        bf16x8 afr[MT];
        #pragma unroll
        for (int mt=0;mt<MT;mt++){
            int row = mt*16 + li;
            afr[mt] = *(const bf16x8*)(Zl + row*KP + ks*32 + quad*8);
        }
        #pragma unroll
        for (int mt=0;mt<MT;mt++)
            #pragma unroll
            for (int t=0;t<4;t++)
                acc[mt][t] = __builtin_amdgcn_mfma_f32_16x16x32_bf16(afr[mt], bfr[t], acc[mt][t], 0, 0, 0);
    }
}

// ---------------- stats pass: per-channel sum & sumsq of z@W ----------------
__global__ __launch_bounds__(256) void k_stats(
    const unsigned short* __restrict__ node_src, const unsigned short* __restrict__ edge_src,
    const int* __restrict__ eidx, const unsigned short* __restrict__ Wpk,
    float* __restrict__ sumv, float* __restrict__ sumq)
{
    __shared__ unsigned short Zl[RPB*KP];
    const int tid = threadIdx.x, w = tid>>6, lane = tid&63;
    const int n0 = blockIdx.x * NPB;
    stage_z(Zl, node_src, edge_src, eidx, n0, tid);
    __syncthreads();
    f32x4 acc[MT][4];
    mfma_core(Zl, Wpk, w, lane, acc);
    const int quad = lane>>4, li = lane&15;
    #pragma unroll
    for (int t=0;t<4;t++){
        float s=0.f, q=0.f;
        #pragma unroll
        for (int mt=0;mt<MT;mt++)
            #pragma unroll
            for (int r=0;r<4;r++){ float v = acc[mt][t][r]; s+=v; q = fmaf(v,v,q); }
        s += __shfl_xor(s,16); s += __shfl_xor(s,32);
        q += __shfl_xor(q,16); q += __shfl_xor(q,32);
        if (quad == 0) {
            int col = t*64 + w*16 + li;
            atomicAdd(&sumv[col], s);
            atomicAdd(&sumq[col], q);
        }
    }
}

// ---------------- finalize: scale = rsqrt(var+eps), bias = -mean*scale ----------------
__global__ __launch_bounds__(256) void k_fin(const float* __restrict__ s,
    const float* __restrict__ q, float* __restrict__ sc, float* __restrict__ bs,
    float inv_cnt, int ncols)
{
    int t = threadIdx.x;
    if (t < ncols) {
        float mm = s[t]*inv_cnt;
        float v  = q[t]*inv_cnt - mm*mm;
        float is = rsqrtf(v + 1e-5f);
        sc[t] = is;
        bs[t] = -mm*is;
    }
}

// combined finalize: aggr stats (64, 1/NN) + g stats (41, 1/NM)
__global__ __launch_bounds__(128) void k_fin2(
    const float* __restrict__ aS, const float* __restrict__ aQ,
    float* __restrict__ sA, float* __restrict__ bA,
    const float* __restrict__ gS, const float* __restrict__ gQ,
    float* __restrict__ sG, float* __restrict__ bG)
{
    int t = threadIdx.x;
    if (t < 64) {
        float mm = aS[t]*(1.f/(float)NN);
        float v  = aQ[t]*(1.f/(float)NN) - mm*mm;
        float is = rsqrtf(v + 1e-5f);
        sA[t] = is; bA[t] = -mm*is;
    } else if (t < 64+EE) {
        int c = t-64;
        float mm = gS[c]*(1.f/(float)NM);
        float v  = gQ[c]*(1.f/(float)NM) - mm*mm;
        float is = rsqrtf(v + 1e-5f);
        sG[c] = is; bG[c] = -mm*is;
    }
}

// ---------------- apply pass: BN + gates, node aggr + edge g + their stats ----------------
__global__ __launch_bounds__(256) void k_apply(
    const unsigned short* __restrict__ node_src, const unsigned short* __restrict__ edge_src,
    const int* __restrict__ eidx, const unsigned short* __restrict__ Wpk,
    const float* __restrict__ sPre, const float* __restrict__ bPre,
    float* __restrict__ aggr, unsigned short* __restrict__ gbuf,
    float* __restrict__ aS, float* __restrict__ aQ,
    float* __restrict__ gS, float* __restrict__ gQ)
{
    __shared__ __align__(16) char smem[RPB*KP*2];   // 38400 B; gL [96][68] fp32 aliases after sync
    unsigned short* Zl = (unsigned short*)smem;
    float* gL = (float*)smem;
    const int tid = threadIdx.x, w = tid>>6, lane = tid&63;
    const int n0 = blockIdx.x * NPB;
    const int gr0 = n0 * MM;
    stage_z(Zl, node_src, edge_src, eidx, n0, tid);
    __syncthreads();
    f32x4 acc[MT][4];
    mfma_core(Zl, Wpk, w, lane, acc);
    __syncthreads();                          // all waves done reading Zl -> gL may alias

    const int quad = lane>>4, li = lane&15;
    const int cg = w*16 + li;
    const float s0 = sPre[cg],    c0 = bPre[cg];
    const float s1 = sPre[64+cg], c1 = bPre[64+cg];
    // node gates -> LDS [96][68]
    #pragma unroll
    for (int mt=0;mt<MT;mt++)
        #pragma unroll
        for (int r=0;r<4;r++){
            int row = mt*16 + quad*4 + r;
            float nf = fmaf(acc[mt][0][r], s0, c0);
            float nc = fmaf(acc[mt][1][r], s1, c1);
            gL[row*68 + cg] = sigm(nf) * lrelu(nc);
        }
    // edge gates -> global (bf16, padded stride 48) + stats
    float pg = 0.f, pq = 0.f;
    bool ce_ok = cg < EE;
    if (ce_ok) {
        const float s2 = sPre[EFO+cg], c2 = bPre[EFO+cg];
        const float s3 = sPre[ECO+cg], c3 = bPre[ECO+cg];
        #pragma unroll
        for (int mt=0;mt<MT;mt++)
            #pragma unroll
            for (int r=0;r<4;r++){
                int row = mt*16 + quad*4 + r;
                float ef = fmaf(acc[mt][2][r], s2, c2);
                float ec = fmaf(acc[mt][3][r], s3, c3);
                float gv = sigm(ef)*lrelu(ec);
                gbuf[(size_t)(gr0+row)*ES + cg] = f2bf(gv);
                pg += gv; pq = fmaf(gv,gv,pq);
            }
    }
    pg += __shfl_xor(pg,16); pg += __shfl_xor(pg,32);
    pq += __shfl_xor(pq,16); pq += __shfl_xor(pq,32);
    if (quad==0 && ce_ok){ atomicAdd(&gS[cg], pg); atomicAdd(&gQ[cg], pq); }

    __syncthreads();
    if (tid < 64) {
        float sAcc=0.f, sQq=0.f;
        #pragma unroll
        for (int nl=0; nl<NPB; nl++){
            float vsum = 0.f;
            #pragma unroll
            for (int jj=0;jj<MM;jj++) vsum += gL[(nl*MM+jj)*68 + tid];
            aggr[(size_t)(n0+nl)*64 + tid] = vsum;
            sAcc += vsum; sQq = fmaf(vsum,vsum,sQq);
        }
        atomicAdd(&aS[tid], sAcc);
        atomicAdd(&aQ[tid], sQq);
    }
}

// ---------------- residual updates (vectorized 8-wide) ----------------
__global__ __launch_bounds__(256) void k_upd_node(const unsigned short* __restrict__ cur,
    const float* __restrict__ aggr, const float* __restrict__ sA,
    const float* __restrict__ bA, unsigned short* __restrict__ nxt)
{
    int idx = blockIdx.x*256 + threadIdx.x;
    if (idx >= NN*8) return;
    int n = idx >> 3, ch = idx & 7;
    int base = n*64 + ch*8;
    float4 a0 = *(const float4*)(aggr + base);
    float4 a1 = *(const float4*)(aggr + base + 4);
    uint4 cu = *(const uint4*)(cur + base);
    unsigned short cs[8]; *(uint4*)cs = cu;
    float av[8] = {a0.x,a0.y,a0.z,a0.w,a1.x,a1.y,a1.z,a1.w};
    unsigned short os[8];
    #pragma unroll
    for (int j=0;j<8;j++){
        int c = ch*8+j;
        float v = fmaf(av[j], sA[c], bA[c]);
        os[j] = f2bf(lrelu(b2f(cs[j]) + v));
    }
    *(uint4*)(nxt + base) = *(uint4*)os;
}

// edge update in place: e = lrelu(e + BN(g)), pad cols passthrough
__global__ __launch_bounds__(256) void k_upd_edge(unsigned short* __restrict__ e,
    const unsigned short* __restrict__ g, const float* __restrict__ sG,
    const float* __restrict__ bG)
{
    int idx = blockIdx.x*256 + threadIdx.x;
    if (idx >= NM*6) return;
    int gr = idx / 6, ch = idx - gr*6;
    size_t base = (size_t)gr*ES + ch*8;
    uint4 eu = *(const uint4*)(e + base);
    uint4 gu = *(const uint4*)(g + base);
    unsigned short es8[8], gs8[8], os[8];
    *(uint4*)es8 = eu; *(uint4*)gs8 = gu;
    #pragma unroll
    for (int j=0;j<8;j++){
        int c = ch*8+j;
        if (c < EE) {
            float v = fmaf(b2f(gs8[j]), sG[c], bG[c]);
            os[j] = f2bf(lrelu(b2f(es8[j]) + v));
        } else {
            os[j] = es8[j];
        }
    }
    *(uint4*)(e + base) = *(uint4*)os;
}

// ---------------- final heads ----------------
__global__ __launch_bounds__(256) void k_final(
    const unsigned short* __restrict__ node_src, const unsigned short* __restrict__ edge_src,
    const int* __restrict__ eidx, const unsigned short* __restrict__ Wpk,
    const float* __restrict__ sF, const float* __restrict__ bF,
    const float* __restrict__ distb, float* __restrict__ out)
{
    __shared__ __align__(16) char smem[RPB*KP*2];   // 38400 B; bufD/bufC alias after sync
    unsigned short* Zl = (unsigned short*)smem;
    float* bufD = (float*)smem;                     // [96][17] = 6528 B
    float* bufC = (float*)(smem + 8192);            // [96][17]
    const int tid = threadIdx.x, w = tid>>6, lane = tid&63;
    const int n0 = blockIdx.x * NPB;
    const int gr0 = n0 * MM;
    stage_z(Zl, node_src, edge_src, eidx, n0, tid);
    __syncthreads();
    f32x4 acc[MT][4];
    mfma_core(Zl, Wpk, w, lane, acc);
    __syncthreads();                                // Zl dead -> bufD/C alias

    const int quad = lane>>4, li = lane&15;
    const int c = w*16 + li;
    const float s0=sF[c],     b0=bF[c];
    const float s1=sF[64+c],  b1=bF[64+c];
    const float s2=sF[128+c], b2=bF[128+c];
    const float s3=sF[192+c], b3=bF[192+c];
    const int liq = li >> 2;
    const bool wr = (li & 3) == 0;
    #pragma unroll
    for (int mt=0;mt<MT;mt++)
        #pragma unroll
        for (int r=0;r<4;r++){
            int row = mt*16 + quad*4 + r;
            float dv = distb[gr0 + row];
            float pd = softpl(fmaf(acc[mt][0][r],s0,b0) + dv)
                     + softpl(fmaf(acc[mt][1][r],s1,b1) + dv);
            float pc = softpl(fmaf(acc[mt][2][r],s2,b2))
                     + softpl(fmaf(acc[mt][3][r],s3,b3));
            // partial reduce over groups of 4 li (DPP quad_perm)
            pd += __shfl_xor(pd,1); pd += __shfl_xor(pd,2);
            pc += __shfl_xor(pc,1); pc += __shfl_xor(pc,2);
            if (wr) {
                bufD[row*17 + w*4 + liq] = pd;
                bufC[row*17 + w*4 + liq] = pc;
            }
        }
    __syncthreads();
    if (tid < 2*RPB) {
        int h = tid >= RPB;
        int row = tid - (h ? RPB : 0);
        const float* buf = h ? bufC : bufD;
        float s = 0.f;
        #pragma unroll
        for (int t=0;t<16;t++) s += buf[row*17+t];
        size_t gr = gr0 + row;
        out[gr*2 + h] = h ? s * (1.f/128.f) * (1.f/(float)NN) : s * (1.f/128.f);
    }
}

// ---------------- launch ----------------
extern "C" void kernel_launch(void* const* d_in, const int* in_sizes, int n_in,
                              void* d_out, int out_size, void* d_ws, size_t ws_size,
                              hipStream_t stream)
{
    const float* node_fea = (const float*)d_in[0];
    const float* edge_in  = (const float*)d_in[1];
    const float* nbr_off  = (const float*)d_in[2];
    const float* apos     = (const float*)d_in[3];
    const float* cells    = (const float*)d_in[4];
    const int*   eidx     = (const int*)  d_in[5];
    const float* W_emb    = (const float*)d_in[6];
    const float* b_emb    = (const float*)d_in[7];
    const float* W_pn     = (const float*)d_in[8];
    const float* W_pe     = (const float*)d_in[10];
    const float* W_dist   = (const float*)d_in[12];
    const float* W_cst    = (const float*)d_in[14];
    float* out = (float*)d_out;
    char* ws = (char*)d_ws;

    size_t o = 0;
    auto alloc = [&](size_t bytes) { char* p = ws + o; o += (bytes + 255) & ~(size_t)255; return p; };
    unsigned short* node0 = (unsigned short*)alloc((size_t)NN*FF*2);
    unsigned short* node1 = (unsigned short*)alloc((size_t)NN*FF*2);
    unsigned short* ebuf  = (unsigned short*)alloc((size_t)NM*ES*2);
    unsigned short* gbuf  = (unsigned short*)alloc((size_t)NM*ES*2);
    float* aggr  = (float*)alloc((size_t)NN*FF*4);
    float* distb = (float*)alloc((size_t)NM*4);
    unsigned short* Wpk = (unsigned short*)alloc((size_t)4*49152*2);
    float* stats = (float*)alloc(4096*4);
    float* msb   = (float*)alloc(4096*4);

    hipMemsetAsync(stats, 0, 4096*sizeof(float), stream);
    pack_w<<<(4*49152+255)/256, 256, 0, stream>>>(W_pn, W_pe, W_dist, W_cst, Wpk);
    k_dist <<<(NM+255)/256,     256, 0, stream>>>(nbr_off, apos, cells, eidx, distb);
    k_cvt  <<<(NM*ES+255)/256,  256, 0, stream>>>(edge_in, ebuf);
    k_emb  <<<(NN*FF+255)/256,  256, 0, stream>>>(node_fea, W_emb, b_emb, node0);

    const float invNM = 1.f/(float)NM;
    const unsigned short* ncur = node0;

    for (int l=0;l<3;l++){
        float* st = stats + l*768;
        float* ms = msb   + l*768;
        float* preS = st;       float* preQ = st+256;
        float* aSs  = st+512;   float* aQq  = st+576;
        float* gSs  = st+640;   float* gQq  = st+704;
        float* sPre = ms;       float* bPre = ms+256;
        float* sA   = ms+512;   float* bA   = ms+576;
        float* sG   = ms+640;   float* bG   = ms+704;
        const unsigned short* Wl = Wpk + (size_t)l*49152;
        unsigned short* ndst = (l & 1) ? node0 : node1;

        k_stats<<<NBLK,256,0,stream>>>(ncur, ebuf, eidx, Wl, preS, preQ);
        k_fin  <<<1,256,0,stream>>>(preS, preQ, sPre, bPre, invNM, 256);
        k_apply<<<NBLK,256,0,stream>>>(ncur, ebuf, eidx, Wl, sPre, bPre,
                                       aggr, gbuf, aSs, aQq, gSs, gQq);
        k_fin2 <<<1,128,0,stream>>>(aSs, aQq, sA, bA, gSs, gQq, sG, bG);
        k_upd_node<<<(NN*8+255)/256,256,0,stream>>>(ncur, aggr, sA, bA, ndst);
        k_upd_edge<<<(NM*6+255)/256,256,0,stream>>>(ebuf, gbuf, sG, bG);
        ncur = ndst;
    }

    float* fS = stats + 3*768; float* fQ = fS + 256;
    float* sF = msb   + 3*768; float* bF = sF + 256;
    k_stats<<<NBLK,256,0,stream>>>(ncur, ebuf, eidx, Wpk + (size_t)3*49152, fS, fQ);
    k_fin  <<<1,256,0,stream>>>(fS, fQ, sF, bF, invNM, 256);
    k_final<<<NBLK,256,0,stream>>>(ncur, ebuf, eidx, Wpk + (size_t)3*49152, sF, bF, distb, out);
}

// Round 6
// 1898.839 us; speedup vs baseline: 4.3605x; 1.1073x over previous
//
#include <hip/hip_runtime.h>
#include <math.h>

// ---------------- problem constants ----------------
#define NN 50000      // nodes
#define MM 12         // neighbors
#define NM 600000     // edges = NN*MM
#define OF 92         // orig node features
#define FF 64         // node feature dim
#define EE 41         // edge feature dim
#define ES 48         // padded edge stride (bf16), cols 41..47 = 0
#define ZZ 169        // 2*FF + EE
#define EFO 128
#define ECO 192
#define RPB 96        // rows (edges) per block = 8 nodes * 12
#define NPB 8         // nodes per block
#define NBLK 6250     // NN / NPB
#define KP 200        // padded K stride (bf16 elements) in LDS
#define KSTEPS 6      // 6 * 32 = 192 >= 169
#define MT 6          // M-tiles per block (96/16)

typedef __bf16 bf16x8 __attribute__((ext_vector_type(8)));
typedef float  f32x4  __attribute__((ext_vector_type(4)));

__device__ __forceinline__ float lrelu(float x){ return fmaxf(x, 0.01f*x); }
__device__ __forceinline__ float sigm(float x){ return __builtin_amdgcn_rcpf(1.f+__expf(-x)); }
__device__ __forceinline__ float softpl(float x){ return fmaxf(x,0.f) + __logf(1.f+__expf(-fabsf(x))); }
__device__ __forceinline__ unsigned short f2bf(float f){
    __bf16 h = (__bf16)f;
    return __builtin_bit_cast(unsigned short, h);
}
__device__ __forceinline__ float b2f(unsigned short u){
    unsigned int b = ((unsigned int)u) << 16;
    return __builtin_bit_cast(float, b);
}
__device__ __forceinline__ unsigned short f2h(float f){
    _Float16 h = (_Float16)f;
    return __builtin_bit_cast(unsigned short, h);
}
__device__ __forceinline__ float h2f(unsigned short u){
    return (float)__builtin_bit_cast(_Float16, u);
}

// ---------------- weight packing into B-fragment layout (bf16) ----------------
__global__ __launch_bounds__(256) void pack_w(const float* __restrict__ Wn,
    const float* __restrict__ We, const float* __restrict__ Wd,
    const float* __restrict__ Wc, unsigned short* __restrict__ dst)
{
    int idx = blockIdx.x*256 + threadIdx.x;
    if (idx >= 4*49152) return;
    int j    = idx & 7;
    int lane = (idx >> 3) & 63;
    int ntks = (idx >> 9) % 96;         // ks*16 + nt
    int L    = idx / 49152;
    int nt = ntks & 15, ks = ntks >> 4;
    int k   = ks*32 + (lane>>4)*8 + j;
    int col = nt*16 + (lane&15);
    float v = 0.f;
    if (k < ZZ) {
        if (L < 3) {
            if (col < 128)                       v = Wn[((size_t)L*ZZ + k)*128 + col];
            else if (col >= EFO && col < EFO+EE) v = We[((size_t)L*ZZ + k)*82 + (col-EFO)];
            else if (col >= ECO && col < ECO+EE) v = We[((size_t)L*ZZ + k)*82 + 41 + (col-ECO)];
        } else {
            if (col < 128) v = Wd[(size_t)k*128 + col];
            else           v = Wc[(size_t)k*128 + (col-128)];
        }
    }
    dst[idx] = f2bf(v);
}

// ---------------- distance ----------------
__global__ __launch_bounds__(256) void k_dist(const float* __restrict__ off,
    const float* __restrict__ apos, const float* __restrict__ cells,
    const int* __restrict__ eidx, float* __restrict__ distb)
{
    int idx = blockIdx.x*256 + threadIdx.x;
    if (idx >= NM) return;
    int n = idx / MM;
    const float* o  = off + (size_t)idx*3;
    const float* cl = cells + (size_t)n*9;
    int n2 = eidx[idx];
    float o0=o[0], o1=o[1], o2=o[2];
    float dd = 1e-12f;
    #pragma unroll
    for (int j=0;j<3;j++){
        float oc = o0*cl[0*3+j] + o1*cl[1*3+j] + o2*cl[2*3+j];
        float d = apos[(size_t)n2*3+j] + oc - apos[(size_t)n*3+j];
        dd += d*d;
    }
    distb[idx] = sqrtf(dd);
}

// ---------------- edge convert: fp32 [NM][41] -> bf16 [NM][48] (pad 0) ----------------
__global__ __launch_bounds__(256) void k_cvt(const float* __restrict__ src,
    unsigned short* __restrict__ e)
{
    int idx = blockIdx.x*256 + threadIdx.x;
    if (idx >= NM*ES) return;
    int gr = idx / ES;
    int c  = idx - gr*ES;
    e[idx] = (c < EE) ? f2bf(src[(size_t)gr*EE + c]) : (unsigned short)0;
}

// ---------------- embedding: node0 = bf16(node_fea @ W_emb + b_emb) ----------------
__global__ __launch_bounds__(256) void k_emb(const float* __restrict__ nf,
    const float* __restrict__ W, const float* __restrict__ b,
    unsigned short* __restrict__ node0)
{
    int idx = blockIdx.x*256 + threadIdx.x;
    if (idx >= NN*FF) return;
    int n = idx >> 6, c = idx & 63;
    float s = b[c];
    for (int k=0;k<OF;k++) s = fmaf(nf[(size_t)n*OF+k], W[k*FF+c], s);
    node0[idx] = f2bf(s);
}

// ---------------- z staging into LDS: bf16 [96][KP], three branch-free sections ----------------
__device__ __forceinline__ void stage_z(unsigned short* __restrict__ Zl,
    const unsigned short* __restrict__ node_src, const unsigned short* __restrict__ edge_src,
    const int* __restrict__ eidx, int n0, int tid)
{
    const int gr0 = n0 * MM;
    // self node: chunks 0..7 (cols 0..63)
    #pragma unroll
    for (int it=0; it<3; ++it){
        int i = it*256 + tid;           // 0..767
        int row = i >> 3, ch = i & 7;
        int n = n0 + row/MM;
        uint4 v = *(const uint4*)(node_src + (size_t)n*FF + ch*8);
        *(uint4*)(Zl + row*KP + ch*8) = v;
    }
    // neighbor node (gather): chunks 8..15 (cols 64..127)
    #pragma unroll
    for (int it=0; it<3; ++it){
        int i = it*256 + tid;
        int row = i >> 3, ch = i & 7;
        int n2 = eidx[gr0 + row];
        uint4 v = *(const uint4*)(node_src + (size_t)n2*FF + ch*8);
        *(uint4*)(Zl + row*KP + 64 + ch*8) = v;
    }
    // edge features: chunks 16..21 real, 22..23 zero (cols 128..191)
    #pragma unroll
    for (int it=0; it<3; ++it){
        int i = it*256 + tid;
        int row = i >> 3, ch = i & 7;
        uint4 v = make_uint4(0u,0u,0u,0u);
        if (ch < 6) v = *(const uint4*)(edge_src + (size_t)(gr0+row)*ES + ch*8);
        *(uint4*)(Zl + row*KP + 128 + ch*8) = v;
    }
}

// ---------------- MFMA core: 6 M-tiles x 4 col-group tiles per wave ----------------
__device__ __forceinline__ void mfma_core(const unsigned short* __restrict__ Zl,
    const unsigned short* __restrict__ Wpk, int w, int lane, f32x4 (&acc)[MT][4])
{
    const int quad = lane >> 4, li = lane & 15;
    #pragma unroll
    for (int mt=0;mt<MT;mt++)
        #pragma unroll
        for (int t=0;t<4;t++) acc[mt][t] = (f32x4){0.f,0.f,0.f,0.f};

    #pragma unroll 2
    for (int ks=0; ks<KSTEPS; ++ks) {
        bf16x8 bfr[4];
        #pragma unroll
        for (int t=0;t<4;t++){
            int nt = w + 4*t;
            bfr[t] = *(const bf16x8*)(Wpk + (((ks*16 + nt)*64 + lane) << 3));
        }
        bf16x8 afr[MT];
        #pragma unroll
        for (int mt=0;mt<MT;mt++){
            int row = mt*16 + li;
            afr[mt] = *(const bf16x8*)(Zl + row*KP + ks*32 + quad*8);
        }
        #pragma unroll
        for (int mt=0;mt<MT;mt++)
            #pragma unroll
            for (int t=0;t<4;t++)
                acc[mt][t] = __builtin_amdgcn_mfma_f32_16x16x32_bf16(afr[mt], bfr[t], acc[mt][t], 0, 0, 0);
    }
}

// ---------------- stats epilogue (shared) ----------------
__device__ __forceinline__ void stats_epi(const f32x4 (&acc)[MT][4], int w, int lane,
    float* __restrict__ sumv, float* __restrict__ sumq)
{
    const int quad = lane>>4, li = lane&15;
    #pragma unroll
    for (int t=0;t<4;t++){
        float s=0.f, q=0.f;
        #pragma unroll
        for (int mt=0;mt<MT;mt++)
            #pragma unroll
            for (int r=0;r<4;r++){ float v = acc[mt][t][r]; s+=v; q = fmaf(v,v,q); }
        s += __shfl_xor(s,16); s += __shfl_xor(s,32);
        q += __shfl_xor(q,16); q += __shfl_xor(q,32);
        if (quad == 0) {
            int col = t*64 + w*16 + li;
            atomicAdd(&sumv[col], s);
            atomicAdd(&sumq[col], q);
        }
    }
}

// ---------------- GEMM + stats (fallback: no Y spill) ----------------
__global__ __launch_bounds__(256) void k_stats(
    const unsigned short* __restrict__ node_src, const unsigned short* __restrict__ edge_src,
    const int* __restrict__ eidx, const unsigned short* __restrict__ Wpk,
    float* __restrict__ sumv, float* __restrict__ sumq)
{
    __shared__ unsigned short Zl[RPB*KP];
    const int tid = threadIdx.x, w = tid>>6, lane = tid&63;
    const int n0 = blockIdx.x * NPB;
    stage_z(Zl, node_src, edge_src, eidx, n0, tid);
    __syncthreads();
    f32x4 acc[MT][4];
    mfma_core(Zl, Wpk, w, lane, acc);
    stats_epi(acc, w, lane, sumv, sumq);
}

// ---------------- GEMM + stats + Y spill (fp16, C-fragment tile layout) ----------------
__global__ __launch_bounds__(256) void k_gemm(
    const unsigned short* __restrict__ node_src, const unsigned short* __restrict__ edge_src,
    const int* __restrict__ eidx, const unsigned short* __restrict__ Wpk,
    float* __restrict__ sumv, float* __restrict__ sumq, ushort4* __restrict__ Y)
{
    __shared__ unsigned short Zl[RPB*KP];
    const int tid = threadIdx.x, w = tid>>6, lane = tid&63;
    const int b = blockIdx.x;
    const int n0 = b * NPB;
    stage_z(Zl, node_src, edge_src, eidx, n0, tid);
    __syncthreads();
    f32x4 acc[MT][4];
    mfma_core(Zl, Wpk, w, lane, acc);
    #pragma unroll
    for (int mt=0;mt<MT;mt++)
        #pragma unroll
        for (int t=0;t<4;t++){
            ushort4 h;
            h.x = f2h(acc[mt][t][0]); h.y = f2h(acc[mt][t][1]);
            h.z = f2h(acc[mt][t][2]); h.w = f2h(acc[mt][t][3]);
            Y[((size_t)b*96 + mt*16 + t*4 + w)*64 + lane] = h;
        }
    stats_epi(acc, w, lane, sumv, sumq);
}

// ---------------- apply epilogue core (shared by both apply variants) ----------------
__device__ __forceinline__ void apply_epi(float (&vals)[4], int mt,
    int quad, int cg, bool ce_ok, const float sc[4], const float bi[4],
    int r, int gr0, float* __restrict__ gL, unsigned short* __restrict__ gbuf,
    float& pg, float& pq)
{
    int row = mt*16 + quad*4 + r;
    float nf = fmaf(vals[0], sc[0], bi[0]);
    float nc = fmaf(vals[1], sc[1], bi[1]);
    gL[row*68 + cg] = sigm(nf) * lrelu(nc);
    if (ce_ok) {
        float ef = fmaf(vals[2], sc[2], bi[2]);
        float ec = fmaf(vals[3], sc[3], bi[3]);
        float gv = sigm(ef)*lrelu(ec);
        gbuf[(size_t)(gr0+row)*ES + cg] = f2bf(gv);
        pg += gv; pq = fmaf(gv,gv,pq);
    }
}

__device__ __forceinline__ void apply_tail(float pg, float pq, int tid, int quad,
    int cg, bool ce_ok, int n0, const float* __restrict__ gL,
    float* __restrict__ aggr, float* __restrict__ aS, float* __restrict__ aQ,
    float* __restrict__ gS, float* __restrict__ gQ)
{
    pg += __shfl_xor(pg,16); pg += __shfl_xor(pg,32);
    pq += __shfl_xor(pq,16); pq += __shfl_xor(pq,32);
    if (quad==0 && ce_ok){ atomicAdd(&gS[cg], pg); atomicAdd(&gQ[cg], pq); }
    __syncthreads();
    if (tid < 64) {
        float sAcc=0.f, sQq=0.f;
        #pragma unroll
        for (int nl=0; nl<NPB; nl++){
            float vsum = 0.f;
            #pragma unroll
            for (int jj=0;jj<MM;jj++) vsum += gL[(nl*MM+jj)*68 + tid];
            aggr[(size_t)(n0+nl)*64 + tid] = vsum;
            sAcc += vsum; sQq = fmaf(vsum,vsum,sQq);
        }
        atomicAdd(&aS[tid], sAcc);
        atomicAdd(&aQ[tid], sQq);
    }
}

// ---------------- apply pass, Y path (epilogue-only) ----------------
__global__ __launch_bounds__(256) void k_apply_y(
    const ushort4* __restrict__ Y,
    const float* __restrict__ preS, const float* __restrict__ preQ,
    float* __restrict__ aggr, unsigned short* __restrict__ gbuf,
    float* __restrict__ aS, float* __restrict__ aQ,
    float* __restrict__ gS, float* __restrict__ gQ)
{
    __shared__ float gL[RPB*68];
    const int tid = threadIdx.x, w = tid>>6, lane = tid&63;
    const int quad = lane>>4, li = lane&15;
    const int b = blockIdx.x;
    const int n0 = b * NPB;
    const int gr0 = n0 * MM;
    const int cg = w*16 + li;

    float sc[4], bi[4];
    #pragma unroll
    for (int t=0;t<4;t++){
        int col = t*64 + cg;
        float mm = preS[col]*(1.f/(float)NM);
        float vv = preQ[col]*(1.f/(float)NM) - mm*mm;
        float is = rsqrtf(vv + 1e-5f);
        sc[t] = is; bi[t] = -mm*is;
    }

    float pg = 0.f, pq = 0.f;
    const bool ce_ok = cg < EE;
    #pragma unroll
    for (int mt=0;mt<MT;mt++){
        unsigned short a[4][4];
        #pragma unroll
        for (int t=0;t<4;t++)
            *(ushort4*)a[t] = Y[((size_t)b*96 + mt*16 + t*4 + w)*64 + lane];
        #pragma unroll
        for (int r=0;r<4;r++){
            float vals[4] = {h2f(a[0][r]), h2f(a[1][r]), h2f(a[2][r]), h2f(a[3][r])};
            apply_epi(vals, mt, quad, cg, ce_ok, sc, bi, r, gr0, gL, gbuf, pg, pq);
        }
    }
    apply_tail(pg, pq, tid, quad, cg, ce_ok, n0, gL, aggr, aS, aQ, gS, gQ);
}

// ---------------- apply pass, fallback (recompute GEMM) ----------------
__global__ __launch_bounds__(256) void k_apply_re(
    const unsigned short* __restrict__ node_src, const unsigned short* __restrict__ edge_src,
    const int* __restrict__ eidx, const unsigned short* __restrict__ Wpk,
    const float* __restrict__ preS, const float* __restrict__ preQ,
    float* __restrict__ aggr, unsigned short* __restrict__ gbuf,
    float* __restrict__ aS, float* __restrict__ aQ,
    float* __restrict__ gS, float* __restrict__ gQ)
{
    __shared__ __align__(16) char smem[RPB*KP*2];   // Zl; gL [96][68] aliases after sync
    unsigned short* Zl = (unsigned short*)smem;
    float* gL = (float*)smem;
    const int tid = threadIdx.x, w = tid>>6, lane = tid&63;
    const int quad = lane>>4, li = lane&15;
    const int n0 = blockIdx.x * NPB;
    const int gr0 = n0 * MM;
    stage_z(Zl, node_src, edge_src, eidx, n0, tid);
    __syncthreads();
    f32x4 acc[MT][4];
    mfma_core(Zl, Wpk, w, lane, acc);
    __syncthreads();                 // Zl dead -> gL may alias

    const int cg = w*16 + li;
    float sc[4], bi[4];
    #pragma unroll
    for (int t=0;t<4;t++){
        int col = t*64 + cg;
        float mm = preS[col]*(1.f/(float)NM);
        float vv = preQ[col]*(1.f/(float)NM) - mm*mm;
        float is = rsqrtf(vv + 1e-5f);
        sc[t] = is; bi[t] = -mm*is;
    }
    float pg = 0.f, pq = 0.f;
    const bool ce_ok = cg < EE;
    #pragma unroll
    for (int mt=0;mt<MT;mt++)
        #pragma unroll
        for (int r=0;r<4;r++){
            float vals[4] = {acc[mt][0][r], acc[mt][1][r], acc[mt][2][r], acc[mt][3][r]};
            apply_epi(vals, mt, quad, cg, ce_ok, sc, bi, r, gr0, gL, gbuf, pg, pq);
        }
    apply_tail(pg, pq, tid, quad, cg, ce_ok, n0, gL, aggr, aS, aQ, gS, gQ);
}

// ---------------- residual updates (scale/bias inline from raw sums) ----------------
__global__ __launch_bounds__(256) void k_upd_node(const unsigned short* __restrict__ cur,
    const float* __restrict__ aggr, const float* __restrict__ aS,
    const float* __restrict__ aQ, unsigned short* __restrict__ nxt)
{
    int idx = blockIdx.x*256 + threadIdx.x;
    if (idx >= NN*8) return;
    int n = idx >> 3, ch = idx & 7;
    int base = n*64 + ch*8;
    float4 a0 = *(const float4*)(aggr + base);
    float4 a1 = *(const float4*)(aggr + base + 4);
    uint4 cu = *(const uint4*)(cur + base);
    unsigned short cs[8]; *(uint4*)cs = cu;
    float av[8] = {a0.x,a0.y,a0.z,a0.w,a1.x,a1.y,a1.z,a1.w};
    unsigned short os[8];
    #pragma unroll
    for (int j=0;j<8;j++){
        int c = ch*8+j;
        float mm = aS[c]*(1.f/(float)NN);
        float vv = aQ[c]*(1.f/(float)NN) - mm*mm;
        float is = rsqrtf(vv + 1e-5f);
        float v = (av[j] - mm) * is;
        os[j] = f2bf(lrelu(b2f(cs[j]) + v));
    }
    *(uint4*)(nxt + base) = *(uint4*)os;
}

__global__ __launch_bounds__(256) void k_upd_edge(unsigned short* __restrict__ e,
    const unsigned short* __restrict__ g, const float* __restrict__ gS,
    const float* __restrict__ gQ)
{
    int idx = blockIdx.x*256 + threadIdx.x;
    if (idx >= NM*6) return;
    int gr = idx / 6, ch = idx - gr*6;
    size_t base = (size_t)gr*ES + ch*8;
    uint4 eu = *(const uint4*)(e + base);
    uint4 gu = *(const uint4*)(g + base);
    unsigned short es8[8], gs8[8], os[8];
    *(uint4*)es8 = eu; *(uint4*)gs8 = gu;
    #pragma unroll
    for (int j=0;j<8;j++){
        int c = ch*8+j;
        if (c < EE) {
            float mm = gS[c]*(1.f/(float)NM);
            float vv = gQ[c]*(1.f/(float)NM) - mm*mm;
            float is = rsqrtf(vv + 1e-5f);
            float v = (b2f(gs8[j]) - mm) * is;
            os[j] = f2bf(lrelu(b2f(es8[j]) + v));
        } else {
            os[j] = es8[j];
        }
    }
    *(uint4*)(e + base) = *(uint4*)os;
}

// ---------------- final-head epilogue core ----------------
__device__ __forceinline__ void final_epi(const float vals[4], int mt, int r,
    int quad, int w, int liq, bool wr, const float sc[4], const float bi[4],
    int gr0, const float* __restrict__ distb,
    float* __restrict__ bufD, float* __restrict__ bufC)
{
    int row = mt*16 + quad*4 + r;
    float dv = distb[gr0 + row];
    float pd = softpl(fmaf(vals[0],sc[0],bi[0]) + dv)
             + softpl(fmaf(vals[1],sc[1],bi[1]) + dv);
    float pc = softpl(fmaf(vals[2],sc[2],bi[2]))
             + softpl(fmaf(vals[3],sc[3],bi[3]));
    pd += __shfl_xor(pd,1); pd += __shfl_xor(pd,2);
    pc += __shfl_xor(pc,1); pc += __shfl_xor(pc,2);
    if (wr) {
        bufD[row*17 + w*4 + liq] = pd;
        bufC[row*17 + w*4 + liq] = pc;
    }
}

__device__ __forceinline__ void final_tail(int tid, int gr0,
    const float* __restrict__ bufD, const float* __restrict__ bufC,
    float* __restrict__ out)
{
    __syncthreads();
    if (tid < 2*RPB) {
        int h = tid >= RPB;
        int row = tid - (h ? RPB : 0);
        const float* buf = h ? bufC : bufD;
        float s = 0.f;
        #pragma unroll
        for (int t=0;t<16;t++) s += buf[row*17+t];
        size_t gr = gr0 + row;
        out[gr*2 + h] = h ? s * (1.f/128.f) * (1.f/(float)NN) : s * (1.f/128.f);
    }
}

// ---------------- final heads, Y path ----------------
__global__ __launch_bounds__(256) void k_final_y(
    const ushort4* __restrict__ Y,
    const float* __restrict__ fS, const float* __restrict__ fQ,
    const float* __restrict__ distb, float* __restrict__ out)
{
    __shared__ float bufD[RPB*17];
    __shared__ float bufC[RPB*17];
    const int tid = threadIdx.x, w = tid>>6, lane = tid&63;
    const int quad = lane>>4, li = lane&15;
    const int b = blockIdx.x;
    const int gr0 = b * NPB * MM;
    const int cg = w*16 + li;

    float sc[4], bi[4];
    #pragma unroll
    for (int t=0;t<4;t++){
        int col = t*64 + cg;
        float mm = fS[col]*(1.f/(float)NM);
        float vv = fQ[col]*(1.f/(float)NM) - mm*mm;
        float is = rsqrtf(vv + 1e-5f);
        sc[t] = is; bi[t] = -mm*is;
    }
    const int liq = li >> 2;
    const bool wr = (li & 3) == 0;
    #pragma unroll
    for (int mt=0;mt<MT;mt++){
        unsigned short a[4][4];
        #pragma unroll
        for (int t=0;t<4;t++)
            *(ushort4*)a[t] = Y[((size_t)b*96 + mt*16 + t*4 + w)*64 + lane];
        #pragma unroll
        for (int r=0;r<4;r++){
            float vals[4] = {h2f(a[0][r]), h2f(a[1][r]), h2f(a[2][r]), h2f(a[3][r])};
            final_epi(vals, mt, r, quad, w, liq, wr, sc, bi, gr0, distb, bufD, bufC);
        }
    }
    final_tail(tid, gr0, bufD, bufC, out);
}

// ---------------- final heads, fallback (recompute GEMM) ----------------
__global__ __launch_bounds__(256) void k_final_re(
    const unsigned short* __restrict__ node_src, const unsigned short* __restrict__ edge_src,
    const int* __restrict__ eidx, const unsigned short* __restrict__ Wpk,
    const float* __restrict__ fS, const float* __restrict__ fQ,
    const float* __restrict__ distb, float* __restrict__ out)
{
    __shared__ __align__(16) char smem[RPB*KP*2];   // Zl; bufD/bufC alias after sync
    unsigned short* Zl = (unsigned short*)smem;
    float* bufD = (float*)smem;                     // [96][17]
    float* bufC = (float*)(smem + 8192);
    const int tid = threadIdx.x, w = tid>>6, lane = tid&63;
    const int quad = lane>>4, li = lane&15;
    const int n0 = blockIdx.x * NPB;
    const int gr0 = n0 * MM;
    stage_z(Zl, node_src, edge_src, eidx, n0, tid);
    __syncthreads();
    f32x4 acc[MT][4];
    mfma_core(Zl, Wpk, w, lane, acc);
    __syncthreads();

    const int cg = w*16 + li;
    float sc[4], bi[4];
    #pragma unroll
    for (int t=0;t<4;t++){
        int col = t*64 + cg;
        float mm = fS[col]*(1.f/(float)NM);
        float vv = fQ[col]*(1.f/(float)NM) - mm*mm;
        float is = rsqrtf(vv + 1e-5f);
        sc[t] = is; bi[t] = -mm*is;
    }
    const int liq = li >> 2;
    const bool wr = (li & 3) == 0;
    #pragma unroll
    for (int mt=0;mt<MT;mt++)
        #pragma unroll
        for (int r=0;r<4;r++){
            float vals[4] = {acc[mt][0][r], acc[mt][1][r], acc[mt][2][r], acc[mt][3][r]};
            final_epi(vals, mt, r, quad, w, liq, wr, sc, bi, gr0, distb, bufD, bufC);
        }
    final_tail(tid, gr0, bufD, bufC, out);
}

// ---------------- launch ----------------
extern "C" void kernel_launch(void* const* d_in, const int* in_sizes, int n_in,
                              void* d_out, int out_size, void* d_ws, size_t ws_size,
                              hipStream_t stream)
{
    const float* node_fea = (const float*)d_in[0];
    const float* edge_in  = (const float*)d_in[1];
    const float* nbr_off  = (const float*)d_in[2];
    const float* apos     = (const float*)d_in[3];
    const float* cells    = (const float*)d_in[4];
    const int*   eidx     = (const int*)  d_in[5];
    const float* W_emb    = (const float*)d_in[6];
    const float* b_emb    = (const float*)d_in[7];
    const float* W_pn     = (const float*)d_in[8];
    const float* W_pe     = (const float*)d_in[10];
    const float* W_dist   = (const float*)d_in[12];
    const float* W_cst    = (const float*)d_in[14];
    float* out = (float*)d_out;
    char* ws = (char*)d_ws;

    size_t o = 0;
    auto alloc = [&](size_t bytes) { char* p = ws + o; o += (bytes + 255) & ~(size_t)255; return p; };
    unsigned short* node0 = (unsigned short*)alloc((size_t)NN*FF*2);
    unsigned short* node1 = (unsigned short*)alloc((size_t)NN*FF*2);
    unsigned short* ebuf  = (unsigned short*)alloc((size_t)NM*ES*2);
    unsigned short* gbuf  = (unsigned short*)alloc((size_t)NM*ES*2);
    float* aggr  = (float*)alloc((size_t)NN*FF*4);
    float* distb = (float*)alloc((size_t)NM*4);
    unsigned short* Wpk = (unsigned short*)alloc((size_t)4*49152*2);
    float* stats = (float*)alloc(4096*4);

    // Y buffer (fp16 pre-BN GEMM output, 307.2 MB) only if workspace allows
    const size_t YB = (size_t)NBLK*96*64*8;
    const bool useY = (o + YB) <= ws_size;
    ushort4* Ybuf = useY ? (ushort4*)alloc(YB) : (ushort4*)nullptr;

    hipMemsetAsync(stats, 0, 4096*sizeof(float), stream);
    pack_w<<<(4*49152+255)/256, 256, 0, stream>>>(W_pn, W_pe, W_dist, W_cst, Wpk);
    k_dist <<<(NM+255)/256,     256, 0, stream>>>(nbr_off, apos, cells, eidx, distb);
    k_cvt  <<<(NM*ES+255)/256,  256, 0, stream>>>(edge_in, ebuf);
    k_emb  <<<(NN*FF+255)/256,  256, 0, stream>>>(node_fea, W_emb, b_emb, node0);

    const unsigned short* ncur = node0;

    for (int l=0;l<3;l++){
        float* st = stats + l*768;
        float* preS = st;       float* preQ = st+256;
        float* aSs  = st+512;   float* aQq  = st+576;
        float* gSs  = st+640;   float* gQq  = st+704;
        const unsigned short* Wl = Wpk + (size_t)l*49152;
        unsigned short* ndst = (l & 1) ? node0 : node1;

        if (useY) {
            k_gemm   <<<NBLK,256,0,stream>>>(ncur, ebuf, eidx, Wl, preS, preQ, Ybuf);
            k_apply_y<<<NBLK,256,0,stream>>>(Ybuf, preS, preQ, aggr, gbuf, aSs, aQq, gSs, gQq);
        } else {
            k_stats  <<<NBLK,256,0,stream>>>(ncur, ebuf, eidx, Wl, preS, preQ);
            k_apply_re<<<NBLK,256,0,stream>>>(ncur, ebuf, eidx, Wl, preS, preQ,
                                              aggr, gbuf, aSs, aQq, gSs, gQq);
        }
        k_upd_node<<<(NN*8+255)/256,256,0,stream>>>(ncur, aggr, aSs, aQq, ndst);
        k_upd_edge<<<(NM*6+255)/256,256,0,stream>>>(ebuf, gbuf, gSs, gQq);
        ncur = ndst;
    }

    float* fS = stats + 3*768; float* fQ = fS + 256;
    const unsigned short* Wf = Wpk + (size_t)3*49152;
    if (useY) {
        k_gemm   <<<NBLK,256,0,stream>>>(ncur, ebuf, eidx, Wf, fS, fQ, Ybuf);
        k_final_y<<<NBLK,256,0,stream>>>(Ybuf, fS, fQ, distb, out);
    } else {
        k_stats  <<<NBLK,256,0,stream>>>(ncur, ebuf, eidx, Wf, fS, fQ);
        k_final_re<<<NBLK,256,0,stream>>>(ncur, ebuf, eidx, Wf, fS, fQ, distb, out);
    }
}